// Round 10
// baseline (7568.488 us; speedup 1.0000x reference)
//
#include <hip/hip_runtime.h>

typedef unsigned short u16;
typedef unsigned int u32;
typedef __bf16 bf16x8 __attribute__((ext_vector_type(8)));
typedef float f32x4 __attribute__((ext_vector_type(4)));
typedef u32 u32x4 __attribute__((ext_vector_type(4)));
typedef u16 u16x4 __attribute__((ext_vector_type(4)));

#define NH 2048
#define BATCH 256
#define NIN 1024
#define NOUT 256
#define LAY 4
#define TSS 32
#define BK 64

#define WAITVM(N) asm volatile("s_waitcnt vmcnt(" #N ")" ::: "memory")

__device__ __forceinline__ u16 f2bf(float f) {
  u32 u = __builtin_bit_cast(u32, f);
  u = (u + 0x7FFFu + ((u >> 16) & 1u)) >> 16;
  return (u16)u;
}
__device__ __forceinline__ float bf2f(u16 h) {
  u32 u = ((u32)h) << 16;
  return __builtin_bit_cast(float, u);
}

// sin for |x| <= ~6, abs err < ~4e-6 (degree-9 odd, pi range reduction)
__device__ __forceinline__ float fast_sin(float x) {
  float k = __builtin_rintf(x * 0.3183098861837907f);
  float r = __builtin_fmaf(k, -3.14159274101257324f, x);
  r = __builtin_fmaf(k, 8.742277657347586e-08f, r);
  float s = r * r;
  float p = __builtin_fmaf(s, 2.75573192e-06f, -1.98412698e-04f);
  p = __builtin_fmaf(s, p, 8.33333333e-03f);
  p = __builtin_fmaf(s, p, -1.66666667e-01f);
  p = r + r * s * p;
  int ki = (int)k;
  return (ki & 1) ? -p : p;
}

__device__ __forceinline__ bf16x8 ld_frag(const u16* p) {
  u32x4 r = *(const u32x4*)p;
  return __builtin_bit_cast(bf16x8, r);
}

__device__ __forceinline__ f32x4 mfma16(bf16x8 a, bf16x8 b, f32x4 c) {
  return __builtin_amdgcn_mfma_f32_16x16x32_bf16(a, b, c, 0, 0, 0);
}

__device__ __forceinline__ void gload16(const u16* g, u16* lds) {
  __builtin_amdgcn_global_load_lds(
      (__attribute__((address_space(1))) u32*)g,
      (__attribute__((address_space(3))) u32*)lds, 16, 0, 0);
}

// manual grid barrier: monotonic counter, device-scope fences.
// Safe because grid=256 with 160 KB LDS -> exactly 1 block/CU -> all blocks
// co-resident. Counter zeroed by host memset each call (graph-replay-safe).
__device__ __forceinline__ void gbar(u32* bar, u32 ep) {
  __threadfence();                    // release this block's writes
  __builtin_amdgcn_s_barrier();
  if (threadIdx.x == 0) {
    __hip_atomic_fetch_add(bar, 1u, __ATOMIC_RELEASE, __HIP_MEMORY_SCOPE_AGENT);
    while (__hip_atomic_load(bar, __ATOMIC_ACQUIRE, __HIP_MEMORY_SCOPE_AGENT) <
           256u * ep) {
      __builtin_amdgcn_s_sleep(2);
    }
  }
  __builtin_amdgcn_s_barrier();
  __threadfence();                    // acquire: invalidate before remote reads
}

// ---------------- pack / convert kernels ----------------

__global__ __launch_bounds__(256) void k_cvt(const float* __restrict__ in,
                                             u16* __restrict__ out, int n4) {
  int i = blockIdx.x * 256 + threadIdx.x;
  if (i >= n4) return;
  f32x4 v = ((const f32x4*)in)[i];
  u16x4 o;
  #pragma unroll
  for (int j = 0; j < 4; j++) o[j] = f2bf(v[j]);
  ((u16x4*)out)[i] = o;
}

__global__ __launch_bounds__(256) void k_split2(const float* __restrict__ in,
                                                u16* __restrict__ hi,
                                                u16* __restrict__ lo, int n4) {
  int i = blockIdx.x * 256 + threadIdx.x;
  if (i >= n4) return;
  f32x4 v = ((const f32x4*)in)[i];
  u16x4 hv, lv;
  #pragma unroll
  for (int j = 0; j < 4; j++) {
    u16 h = f2bf(v[j]);
    hv[j] = h;
    lv[j] = f2bf(v[j] - bf2f(h));
  }
  ((u16x4*)hi)[i] = hv;
  ((u16x4*)lo)[i] = lv;
}

// ---------------- generic GEMM (r5-proven 2-phase structure) ----------------
// Used for x_in projection always, and as the recurrent fallback path.

struct GemmArgs {
  const u16* A[4];
  const u16* B[4];
  void* G;
  int ldA, ldB, kiters, nl;
};

template <int OBF, int NKS>
__global__ __launch_bounds__(256, 2) void k_gemm(GemmArgs args) {
  __shared__ alignas(16) u16 Ab[2][128 * BK];
  __shared__ alignas(16) u16 Bb[2][128 * BK];

  int bid = blockIdx.x;
  int nl = args.nl;
  int l = bid % nl;
  int t1 = bid / nl;
  int ks = t1 & (NKS - 1);
  int t2 = t1 / NKS;
  int nt = t2 & 15;
  int mt = t2 >> 4;

  int tid = threadIdx.x;
  int w = tid >> 6, lane = tid & 63;
  int l15 = lane & 15, l4 = lane >> 4;
  int ldA = args.ldA, ldB = args.ldB;
  int kiters = args.kiters;

  const u16* Ag = args.A[l] + (size_t)(mt * 128) * ldA + ks * (kiters * BK);
  const u16* Bg = args.B[l] + (size_t)(nt * 128) * ldB + ks * (kiters * BK);

  int srow = w * 32 + (lane >> 3);
  int csrc = ((lane & 7) ^ (lane >> 3)) * 8;
  int agoff[4], bgoff[4], lbase[4];
  #pragma unroll
  for (int j = 0; j < 4; j++) {
    agoff[j] = (srow + j * 8) * ldA + csrc;
    bgoff[j] = (srow + j * 8) * ldB + csrc;
    lbase[j] = w * 2048 + j * 512;
  }

  int wr = w >> 1, wc = w & 1;

  f32x4 zero = {0.f, 0.f, 0.f, 0.f};
  f32x4 acc[4][4];
  #pragma unroll
  for (int m = 0; m < 4; m++)
    #pragma unroll
    for (int n = 0; n < 4; n++) acc[m][n] = zero;

  auto stage = [&](int bufi, int kb) {
    int k0 = kb * BK;
    #pragma unroll
    for (int j = 0; j < 4; j++) {
      gload16(Ag + agoff[j] + k0, &Ab[bufi][lbase[j]]);
      gload16(Bg + bgoff[j] + k0, &Bb[bufi][lbase[j]]);
    }
  };
  auto compute = [&](int bufi) {
    #pragma unroll
    for (int kk = 0; kk < 2; kk++) {
      int swz = ((kk * 4 + l4) ^ (l15 & 7)) * 8;
      bf16x8 a[4], b[4];
      #pragma unroll
      for (int m = 0; m < 4; m++)
        a[m] = ld_frag(&Ab[bufi][(wr * 64 + m * 16 + l15) * BK + swz]);
      #pragma unroll
      for (int n = 0; n < 4; n++)
        b[n] = ld_frag(&Bb[bufi][(wc * 64 + n * 16 + l15) * BK + swz]);
      #pragma unroll
      for (int m = 0; m < 4; m++)
        #pragma unroll
        for (int n = 0; n < 4; n++)
          acc[m][n] = mfma16(a[m], b[n], acc[m][n]);
    }
  };

  stage(0, 0);
  stage(1, 1);

  int cur = 0;
  for (int kb = 0; kb < kiters - 2; kb++) {
    WAITVM(8);
    __builtin_amdgcn_s_barrier();
    compute(cur);
    __builtin_amdgcn_s_barrier();
    stage(cur, kb + 2);
    cur ^= 1;
  }
  WAITVM(8);
  __builtin_amdgcn_s_barrier();
  compute(cur);
  cur ^= 1;
  WAITVM(0);
  __builtin_amdgcn_s_barrier();
  compute(cur);

  size_t obase = ((size_t)(ks * nl + l) * BATCH + mt * 128) * NH + nt * 128;
  if (OBF) {
    u16* Go = (u16*)args.G + obase;
    #pragma unroll
    for (int m = 0; m < 4; m++) {
      int row = wr * 64 + m * 16 + l4 * 4;
      #pragma unroll
      for (int n = 0; n < 4; n++) {
        int col = wc * 64 + n * 16 + l15;
        #pragma unroll
        for (int r = 0; r < 4; r++)
          Go[(size_t)(row + r) * NH + col] = f2bf(acc[m][n][r]);
      }
    }
  } else {
    float* Go = (float*)args.G + obase;
    #pragma unroll
    for (int m = 0; m < 4; m++) {
      int row = wr * 64 + m * 16 + l4 * 4;
      #pragma unroll
      for (int n = 0; n < 4; n++) {
        int col = wc * 64 + n * 16 + l15;
        #pragma unroll
        for (int r = 0; r < 4; r++)
          Go[(size_t)(row + r) * NH + col] = acc[m][n][r];
      }
    }
  }
}

// ---------------- persistent W-resident RNN kernel --------------------------
// Grid 256 x 512 thr, 160 KB dynamic LDS -> 1 block/CU (all co-resident).
// Decode: l=bid&3, ks=(bid>>2)&3, nt=bid>>4. Block owns W-slice
// [nt*128..+128)xK[ks*512..+512) of layer l, LDS-resident all 32 steps
// (kills the 32 MB/step W re-read). A (h rows, full M=256) staged per step
// in 2x16KB dbuf, BK=32, r5-proven 2-barrier schedule. ks=4 -> 16 G slabs.
// Chain fused (x_in register-resident, r5 4-partial sum order).
// Steps separated by manual atomic grid barrier (gbar).
// LDS: W 128 KB swizzled (chunk64 ^= row&7, 2-way-free) + A 2x[256][32]
// (chunk4 ^= row&3, 4-way on reads - accepted).

struct RnnArgs {
  const u16* Wb;
  u16* h0b;
  u16* h1b;
  u16* Gp;
  const float* xin;
  const float* brec;
  u32* bar;
};

__global__ __launch_bounds__(512, 1) void k_rnn(RnnArgs args) {
  extern __shared__ u16 smem[];
  u16* Wl = smem;            // 65536 elems = 128 KB
  u16* Al = smem + 65536;    // 2 x 8192 elems = 32 KB

  int bid = blockIdx.x;
  int l = bid & 3;
  int ks = (bid >> 2) & 3;
  int nt = bid >> 4;

  int tid = threadIdx.x;
  int w = tid >> 6, lane = tid & 63;
  int l15 = lane & 15, l4 = lane >> 4;
  int wr = w >> 1, wc = w & 1;  // 4M x 2N waves, wave tile 64x64

  // ---- load W slice into LDS (once) ----
  {
    const u16* Wg = args.Wb + (size_t)l * (NH * NH) + ks * 512;
    #pragma unroll
    for (int i = 0; i < 16; i++) {
      int r = i * 8 + w;                 // wave-uniform row
      int csw = lane ^ (r & 7);          // per-lane inverse-swizzled chunk
      gload16(Wg + (size_t)(nt * 128 + r) * NH + csw * 8,
              Wl + (size_t)(i * 512 + w * 64) * 8);
    }
  }
  WAITVM(0);
  __builtin_amdgcn_s_barrier();

  // chain assignment: 4 consecutive elems of (B x NH)
  int gid = bid * 512 + tid;
  int e = gid * 4;
  int col = e & (NH - 1);
  f32x4 p0 = *(const f32x4*)(args.xin + e);  // register-resident x_in

  u16* Go = args.Gp + (size_t)(ks * LAY + l) * (BATCH * NH) + nt * 128;
  u32 ep = 0;

  auto stageA = [&](const u16* Ag, int bufi, int kb) {
    int k0 = kb * 32;
    #pragma unroll
    for (int j = 0; j < 2; j++) {
      int r = j * 128 + w * 16 + (lane >> 2);
      int csw = (lane & 3) ^ (r & 3);
      gload16(Ag + (size_t)r * NH + k0 + csw * 8,
              Al + (size_t)bufi * 8192 + (size_t)(j * 512 + w * 64) * 8);
    }
  };

  for (int t = 0; t < TSS; t++) {
    if (t > 0) {
      const u16* Ag = ((t & 1) ? args.h1b : args.h0b) +
                      (size_t)l * (BATCH * NH) + ks * 512;

      f32x4 zero = {0.f, 0.f, 0.f, 0.f};
      f32x4 acc[4][4];
      #pragma unroll
      for (int m = 0; m < 4; m++)
        #pragma unroll
        for (int n = 0; n < 4; n++) acc[m][n] = zero;

      auto compute = [&](int bufi, int kb) {
        bf16x8 a[4], b[4];
        #pragma unroll
        for (int m = 0; m < 4; m++) {
          int row = wr * 64 + m * 16 + l15;
          a[m] = ld_frag(Al + bufi * 8192 + row * 32 + ((l4 ^ (row & 3)) * 8));
        }
        #pragma unroll
        for (int n = 0; n < 4; n++) {
          int row = wc * 64 + n * 16 + l15;
          int c = kb * 4 + l4;
          b[n] = ld_frag(Wl + row * 512 + ((c ^ (row & 7)) * 8));
        }
        #pragma unroll
        for (int m = 0; m < 4; m++)
          #pragma unroll
          for (int n = 0; n < 4; n++)
            acc[m][n] = mfma16(a[m], b[n], acc[m][n]);
      };

      stageA(Ag, 0, 0);
      stageA(Ag, 1, 1);
      int cur = 0;
      #pragma unroll 1
      for (int kb = 0; kb < 14; kb++) {
        WAITVM(2);
        __builtin_amdgcn_s_barrier();
        compute(cur, kb);
        __builtin_amdgcn_s_barrier();
        stageA(Ag, cur, kb + 2);
        cur ^= 1;
      }
      WAITVM(2);
      __builtin_amdgcn_s_barrier();
      compute(cur, 14);
      cur ^= 1;
      WAITVM(0);
      __builtin_amdgcn_s_barrier();
      compute(cur, 15);

      #pragma unroll
      for (int m = 0; m < 4; m++) {
        int row = wr * 64 + m * 16 + l4 * 4;
        #pragma unroll
        for (int n = 0; n < 4; n++) {
          int cc = wc * 64 + n * 16 + l15;
          #pragma unroll
          for (int r = 0; r < 4; r++)
            Go[(size_t)(row + r) * NH + cc] = f2bf(acc[m][n][r]);
        }
      }
      gbar(args.bar, ++ep);
    }

    // ---- chain phase (r5 4-partial sum order) ----
    u16* hout = (t & 1) ? args.h0b : args.h1b;
    f32x4 pre = p0;
    if (t == 0) {
      #pragma unroll
      for (int lc = 0; lc < LAY; lc++) {
        f32x4 bb = *(const f32x4*)(args.brec + lc * NH + col);
        u16x4 hv;
        #pragma unroll
        for (int j = 0; j < 4; j++) {
          float v = fast_sin(pre[j] + bb[j]);
          pre[j] = v;
          hv[j] = f2bf(v);
        }
        *(u16x4*)(hout + (size_t)lc * (BATCH * NH) + e) = hv;
      }
    } else {
      #pragma unroll
      for (int lc = 0; lc < LAY; lc++) {
        u16x4 g0 = *(const u16x4*)(args.Gp + (size_t)(0 * LAY + lc) * (BATCH * NH) + e);
        u16x4 g1 = *(const u16x4*)(args.Gp + (size_t)(1 * LAY + lc) * (BATCH * NH) + e);
        u16x4 g2 = *(const u16x4*)(args.Gp + (size_t)(2 * LAY + lc) * (BATCH * NH) + e);
        u16x4 g3 = *(const u16x4*)(args.Gp + (size_t)(3 * LAY + lc) * (BATCH * NH) + e);
        f32x4 bb = *(const f32x4*)(args.brec + lc * NH + col);
        u16x4 hv;
        #pragma unroll
        for (int j = 0; j < 4; j++) {
          float gs = (bf2f(g0[j]) + bf2f(g1[j])) + (bf2f(g2[j]) + bf2f(g3[j]));
          float v = fast_sin(pre[j] + gs + bb[j]);
          pre[j] = v;
          hv[j] = f2bf(v);
        }
        *(u16x4*)(hout + (size_t)lc * (BATCH * NH) + e) = hv;
      }
    }
    if (t + 1 < TSS) gbar(args.bar, ++ep);
  }
}

// ---------------- fallback chain (4 partials, r5-proven) --------------------
__global__ __launch_bounds__(256) void k_chain(const u16* __restrict__ Gp,
                                               const float* __restrict__ x_in,
                                               const float* __restrict__ brec,
                                               u16* __restrict__ hout) {
  int i = blockIdx.x * 256 + threadIdx.x;
  int e = i * 4;
  int col = e & (NH - 1);
  f32x4 pre = *(const f32x4*)(x_in + e);
  #pragma unroll
  for (int l = 0; l < LAY; l++) {
    u16x4 g0 = *(const u16x4*)(Gp + (size_t)(0 * LAY + l) * (BATCH * NH) + e);
    u16x4 g1 = *(const u16x4*)(Gp + (size_t)(1 * LAY + l) * (BATCH * NH) + e);
    u16x4 g2 = *(const u16x4*)(Gp + (size_t)(2 * LAY + l) * (BATCH * NH) + e);
    u16x4 g3 = *(const u16x4*)(Gp + (size_t)(3 * LAY + l) * (BATCH * NH) + e);
    f32x4 bb = *(const f32x4*)(brec + l * NH + col);
    u16x4 hv;
    #pragma unroll
    for (int j = 0; j < 4; j++) {
      float v = fast_sin(pre[j] + (bf2f(g0[j]) + bf2f(g1[j])) +
                         (bf2f(g2[j]) + bf2f(g3[j])) + bb[j]);
      pre[j] = v;
      hv[j] = f2bf(v);
    }
    *(u16x4*)(hout + (size_t)l * (BATCH * NH) + e) = hv;
  }
}

// x_in = sum of 6 partial slices + bias (fp32 partials)
__global__ __launch_bounds__(256) void k_xin_fin(const float* __restrict__ Gp2,
                                                 const float* __restrict__ bin,
                                                 float* __restrict__ x_in) {
  int i = blockIdx.x * 256 + threadIdx.x;
  int e = i * 4;
  int col = e & (NH - 1);
  f32x4 s = *(const f32x4*)(bin + col);
  #pragma unroll
  for (int t = 0; t < 6; t++)
    s += *(const f32x4*)(Gp2 + (size_t)t * (BATCH * NH) + e);
  *(f32x4*)(x_in + e) = s;
}

// ---------------- output projection: out = h3 @ (Wh+Wl)^T + b ----------------
__global__ __launch_bounds__(64) void k_gemm_out(const u16* __restrict__ h3,
                                                 const u16* __restrict__ Wh,
                                                 const u16* __restrict__ Wl,
                                                 const float* __restrict__ bout,
                                                 float* __restrict__ out) {
  int bid = blockIdx.x;  // 128 = 8 mt x 16 nt
  int mt = bid & 7, nt = bid >> 3;
  int lane = threadIdx.x;
  int l15 = lane & 15, l4 = lane >> 4;
  f32x4 zero = {0.f, 0.f, 0.f, 0.f};
  f32x4 acc0 = zero, acc1 = zero;
  const u16* a0p = h3 + (size_t)(mt * 32 + l15) * NH + l4 * 8;
  const u16* a1p = a0p + 16 * NH;
  const u16* bhp = Wh + (size_t)(nt * 16 + l15) * NH + l4 * 8;
  const u16* blp = Wl + (size_t)(nt * 16 + l15) * NH + l4 * 8;
  for (int kb = 0; kb < 64; kb++) {
    bf16x8 a0 = ld_frag(a0p + kb * 32);
    bf16x8 a1 = ld_frag(a1p + kb * 32);
    bf16x8 bh = ld_frag(bhp + kb * 32);
    bf16x8 bl = ld_frag(blp + kb * 32);
    acc0 = mfma16(a0, bh, acc0);
    acc0 = mfma16(a0, bl, acc0);
    acc1 = mfma16(a1, bh, acc1);
    acc1 = mfma16(a1, bl, acc1);
  }
  float bo = bout[nt * 16 + l15];
  #pragma unroll
  for (int r = 0; r < 4; r++) {
    out[(size_t)(mt * 32 + l4 * 4 + r) * NOUT + nt * 16 + l15] = acc0[r] + bo;
    out[(size_t)(mt * 32 + 16 + l4 * 4 + r) * NOUT + nt * 16 + l15] = acc1[r] + bo;
  }
}

// ---------------- host ----------------

extern "C" void kernel_launch(void* const* d_in, const int* in_sizes, int n_in,
                              void* d_out, int out_size, void* d_ws, size_t ws_size,
                              hipStream_t stream) {
  const float* X     = (const float*)d_in[0];
  const float* Winw  = (const float*)d_in[1];
  const float* Winb  = (const float*)d_in[2];
  const float* Wrw   = (const float*)d_in[3];
  const float* Wrb   = (const float*)d_in[4];
  const float* Woutw = (const float*)d_in[5];
  const float* Woutb = (const float*)d_in[6];
  float* out = (float*)d_out;

  char* ws = (char*)d_ws;
  u16* Wb     = (u16*)(ws);                    // 32 MB  bf16 W_rec
  u16* h0     = (u16*)(ws + 33554432);         // 4 MB
  u16* h1     = (u16*)(ws + 37748736);         // 4 MB
  float* xin  = (float*)(ws + 41943040);       // 2 MB
  u16* Gp     = (u16*)(ws + 44040192);         // 16 MB bf16 (4 ks x 4 l)
  float* Gp2  = (float*)(ws + 60817408);       // 12 MB fp32 (2 ks x 3 terms)
  u16* Xhi    = (u16*)(ws + 73400320);         // 512 KB
  u16* Xlo    = (u16*)(ws + 73924608);         // 512 KB
  u16* Winh   = (u16*)(ws + 74448896);         // 4 MB
  u16* Winl   = (u16*)(ws + 78643200);         // 4 MB
  u16* Wouth  = (u16*)(ws + 82837504);         // 1 MB
  u16* Woutl  = (u16*)(ws + 83886080);         // 1 MB
  u32* bar    = (u32*)(ws + 84934656);         // 256 B barrier counter

  // pack weights (every call; stateless)
  k_cvt<<<16384, 256, 0, stream>>>(Wrw, Wb, 4194304);
  k_split2<<<256, 256, 0, stream>>>(X, Xhi, Xlo, 65536);
  k_split2<<<2048, 256, 0, stream>>>(Winw, Winh, Winl, 524288);
  k_split2<<<512, 256, 0, stream>>>(Woutw, Wouth, Woutl, 131072);

  // x_in = X @ W_in^T (+bias), 3-term bf16 split, fp32 partials, split-K 2
  GemmArgs ax;
  ax.A[0] = Xhi; ax.A[1] = Xhi; ax.A[2] = Xlo; ax.A[3] = Xhi;
  ax.B[0] = Winh; ax.B[1] = Winl; ax.B[2] = Winh; ax.B[3] = Winh;
  ax.G = Gp2; ax.ldA = NIN; ax.ldB = NIN; ax.kiters = 8; ax.nl = 3;
  k_gemm<0, 2><<<192, 256, 0, stream>>>(ax);
  k_xin_fin<<<512, 256, 0, stream>>>(Gp2, Winb, xin);

  // persistent W-resident kernel (manual grid barrier; plain launch)
  hipError_t e1 = hipFuncSetAttribute(
      (const void*)k_rnn, hipFuncAttributeMaxDynamicSharedMemorySize, 163840);
  bool persist = (e1 == hipSuccess);
  if (persist) {
    hipMemsetAsync(bar, 0, 256, stream);
    RnnArgs ra;
    ra.Wb = Wb; ra.h0b = h0; ra.h1b = h1; ra.Gp = Gp;
    ra.xin = xin; ra.brec = Wrb; ra.bar = bar;
    k_rnn<<<dim3(256), dim3(512), 163840, stream>>>(ra);
    persist = (hipGetLastError() == hipSuccess);
  }
  if (!persist) {
    // deterministic fallback: r5 separate-kernel loop (same numerics)
    hipMemsetAsync(h0, 0, 4194304, stream);
    u16* hin = h0;
    u16* hout = h1;
    for (int t = 0; t < TSS; t++) {
      GemmArgs ar;
      for (int l = 0; l < 4; l++) {
        ar.A[l] = hin + (size_t)l * (BATCH * NH);
        ar.B[l] = Wb + (size_t)l * (NH * NH);
      }
      ar.G = Gp; ar.ldA = NH; ar.ldB = NH; ar.kiters = 8; ar.nl = 4;
      k_gemm<1, 4><<<512, 256, 0, stream>>>(ar);
      k_chain<<<512, 256, 0, stream>>>(Gp, xin, Wrb, hout);
      u16* tmp = hin; hin = hout; hout = tmp;
    }
  }

  // final layer-3 hidden state lives in h0 (both paths); output projection
  k_gemm_out<<<128, 64, 0, stream>>>(h0 + (size_t)3 * (BATCH * NH), Wouth, Woutl,
                                     Woutb, out);
}

// Round 11
// 5210.833 us; speedup vs baseline: 1.4525x; 1.4525x over previous
//
#include <hip/hip_runtime.h>

typedef unsigned short u16;
typedef unsigned int u32;
typedef __bf16 bf16x8 __attribute__((ext_vector_type(8)));
typedef float f32x4 __attribute__((ext_vector_type(4)));
typedef u32 u32x4 __attribute__((ext_vector_type(4)));
typedef u16 u16x4 __attribute__((ext_vector_type(4)));

#define NH 2048
#define BATCH 256
#define NIN 1024
#define NOUT 256
#define LAY 4
#define TSS 32
#define BK 64

#define WAITVM(N) asm volatile("s_waitcnt vmcnt(" #N ")" ::: "memory")

__device__ __forceinline__ u16 f2bf(float f) {
  u32 u = __builtin_bit_cast(u32, f);
  u = (u + 0x7FFFu + ((u >> 16) & 1u)) >> 16;
  return (u16)u;
}
__device__ __forceinline__ float bf2f(u16 h) {
  u32 u = ((u32)h) << 16;
  return __builtin_bit_cast(float, u);
}

// sin for |x| <= ~6, abs err < ~4e-6 (degree-9 odd, pi range reduction)
__device__ __forceinline__ float fast_sin(float x) {
  float k = __builtin_rintf(x * 0.3183098861837907f);
  float r = __builtin_fmaf(k, -3.14159274101257324f, x);
  r = __builtin_fmaf(k, 8.742277657347586e-08f, r);
  float s = r * r;
  float p = __builtin_fmaf(s, 2.75573192e-06f, -1.98412698e-04f);
  p = __builtin_fmaf(s, p, 8.33333333e-03f);
  p = __builtin_fmaf(s, p, -1.66666667e-01f);
  p = r + r * s * p;
  int ki = (int)k;
  return (ki & 1) ? -p : p;
}

__device__ __forceinline__ bf16x8 ld_frag(const u16* p) {
  u32x4 r = *(const u32x4*)p;
  return __builtin_bit_cast(bf16x8, r);
}

__device__ __forceinline__ f32x4 mfma16(bf16x8 a, bf16x8 b, f32x4 c) {
  return __builtin_amdgcn_mfma_f32_16x16x32_bf16(a, b, c, 0, 0, 0);
}

__device__ __forceinline__ void gload16(const u16* g, u16* lds) {
  __builtin_amdgcn_global_load_lds(
      (__attribute__((address_space(1))) u32*)g,
      (__attribute__((address_space(3))) u32*)lds, 16, 0, 0);
}

// manual grid barrier, r11 fix: RELAXED spin polls (no per-poll cache
// invalidate — r10's ACQUIRE polls had 255 blocks continuously flash-
// invalidating every XCD's L1/L2 for the whole wait -> 7.5 ms).
// Exactly one release fence (waitcnt+wbL2) before arrival and one acquire
// fence (inv) after exit. Safe: grid=256 @ 160 KB LDS -> 1 block/CU, all
// co-resident. Counter zeroed by host memset each call (replay-safe).
__device__ __forceinline__ void gbar(u32* bar, u32 ep) {
  __builtin_amdgcn_fence(__ATOMIC_RELEASE, "agent");  // waitcnt + wbL2 once
  __builtin_amdgcn_s_barrier();
  if (threadIdx.x == 0) {
    __hip_atomic_fetch_add(bar, 1u, __ATOMIC_RELAXED, __HIP_MEMORY_SCOPE_AGENT);
    while (__hip_atomic_load(bar, __ATOMIC_RELAXED, __HIP_MEMORY_SCOPE_AGENT) <
           256u * ep) {
      __builtin_amdgcn_s_sleep(4);
    }
  }
  __builtin_amdgcn_s_barrier();
  __builtin_amdgcn_fence(__ATOMIC_ACQUIRE, "agent");  // single inv
}

// ---------------- pack / convert kernels ----------------

__global__ __launch_bounds__(256) void k_cvt(const float* __restrict__ in,
                                             u16* __restrict__ out, int n4) {
  int i = blockIdx.x * 256 + threadIdx.x;
  if (i >= n4) return;
  f32x4 v = ((const f32x4*)in)[i];
  u16x4 o;
  #pragma unroll
  for (int j = 0; j < 4; j++) o[j] = f2bf(v[j]);
  ((u16x4*)out)[i] = o;
}

__global__ __launch_bounds__(256) void k_split2(const float* __restrict__ in,
                                                u16* __restrict__ hi,
                                                u16* __restrict__ lo, int n4) {
  int i = blockIdx.x * 256 + threadIdx.x;
  if (i >= n4) return;
  f32x4 v = ((const f32x4*)in)[i];
  u16x4 hv, lv;
  #pragma unroll
  for (int j = 0; j < 4; j++) {
    u16 h = f2bf(v[j]);
    hv[j] = h;
    lv[j] = f2bf(v[j] - bf2f(h));
  }
  ((u16x4*)hi)[i] = hv;
  ((u16x4*)lo)[i] = lv;
}

// ---------------- generic GEMM (r5-proven 2-phase structure) ----------------
// Used for x_in projection always, and as the recurrent fallback path.

struct GemmArgs {
  const u16* A[4];
  const u16* B[4];
  void* G;
  int ldA, ldB, kiters, nl;
};

template <int OBF, int NKS>
__global__ __launch_bounds__(256, 2) void k_gemm(GemmArgs args) {
  __shared__ alignas(16) u16 Ab[2][128 * BK];
  __shared__ alignas(16) u16 Bb[2][128 * BK];

  int bid = blockIdx.x;
  int nl = args.nl;
  int l = bid % nl;
  int t1 = bid / nl;
  int ks = t1 & (NKS - 1);
  int t2 = t1 / NKS;
  int nt = t2 & 15;
  int mt = t2 >> 4;

  int tid = threadIdx.x;
  int w = tid >> 6, lane = tid & 63;
  int l15 = lane & 15, l4 = lane >> 4;
  int ldA = args.ldA, ldB = args.ldB;
  int kiters = args.kiters;

  const u16* Ag = args.A[l] + (size_t)(mt * 128) * ldA + ks * (kiters * BK);
  const u16* Bg = args.B[l] + (size_t)(nt * 128) * ldB + ks * (kiters * BK);

  int srow = w * 32 + (lane >> 3);
  int csrc = ((lane & 7) ^ (lane >> 3)) * 8;
  int agoff[4], bgoff[4], lbase[4];
  #pragma unroll
  for (int j = 0; j < 4; j++) {
    agoff[j] = (srow + j * 8) * ldA + csrc;
    bgoff[j] = (srow + j * 8) * ldB + csrc;
    lbase[j] = w * 2048 + j * 512;
  }

  int wr = w >> 1, wc = w & 1;

  f32x4 zero = {0.f, 0.f, 0.f, 0.f};
  f32x4 acc[4][4];
  #pragma unroll
  for (int m = 0; m < 4; m++)
    #pragma unroll
    for (int n = 0; n < 4; n++) acc[m][n] = zero;

  auto stage = [&](int bufi, int kb) {
    int k0 = kb * BK;
    #pragma unroll
    for (int j = 0; j < 4; j++) {
      gload16(Ag + agoff[j] + k0, &Ab[bufi][lbase[j]]);
      gload16(Bg + bgoff[j] + k0, &Bb[bufi][lbase[j]]);
    }
  };
  auto compute = [&](int bufi) {
    #pragma unroll
    for (int kk = 0; kk < 2; kk++) {
      int swz = ((kk * 4 + l4) ^ (l15 & 7)) * 8;
      bf16x8 a[4], b[4];
      #pragma unroll
      for (int m = 0; m < 4; m++)
        a[m] = ld_frag(&Ab[bufi][(wr * 64 + m * 16 + l15) * BK + swz]);
      #pragma unroll
      for (int n = 0; n < 4; n++)
        b[n] = ld_frag(&Bb[bufi][(wc * 64 + n * 16 + l15) * BK + swz]);
      #pragma unroll
      for (int m = 0; m < 4; m++)
        #pragma unroll
        for (int n = 0; n < 4; n++)
          acc[m][n] = mfma16(a[m], b[n], acc[m][n]);
    }
  };

  stage(0, 0);
  stage(1, 1);

  int cur = 0;
  for (int kb = 0; kb < kiters - 2; kb++) {
    WAITVM(8);
    __builtin_amdgcn_s_barrier();
    compute(cur);
    __builtin_amdgcn_s_barrier();
    stage(cur, kb + 2);
    cur ^= 1;
  }
  WAITVM(8);
  __builtin_amdgcn_s_barrier();
  compute(cur);
  cur ^= 1;
  WAITVM(0);
  __builtin_amdgcn_s_barrier();
  compute(cur);

  size_t obase = ((size_t)(ks * nl + l) * BATCH + mt * 128) * NH + nt * 128;
  if (OBF) {
    u16* Go = (u16*)args.G + obase;
    #pragma unroll
    for (int m = 0; m < 4; m++) {
      int row = wr * 64 + m * 16 + l4 * 4;
      #pragma unroll
      for (int n = 0; n < 4; n++) {
        int col = wc * 64 + n * 16 + l15;
        #pragma unroll
        for (int r = 0; r < 4; r++)
          Go[(size_t)(row + r) * NH + col] = f2bf(acc[m][n][r]);
      }
    }
  } else {
    float* Go = (float*)args.G + obase;
    #pragma unroll
    for (int m = 0; m < 4; m++) {
      int row = wr * 64 + m * 16 + l4 * 4;
      #pragma unroll
      for (int n = 0; n < 4; n++) {
        int col = wc * 64 + n * 16 + l15;
        #pragma unroll
        for (int r = 0; r < 4; r++)
          Go[(size_t)(row + r) * NH + col] = acc[m][n][r];
      }
    }
  }
}

// ---------------- persistent W-resident RNN kernel --------------------------
// Identical to r10 except gbar (see above). Grid 256 x 512 thr, 160 KB
// dynamic LDS -> 1 block/CU. Block owns W-slice [nt*128 cols][ks*512 K] of
// layer l, LDS-resident all 32 steps. A staged per step in 2x16KB dbuf,
// BK=32, 2-barrier schedule. 16 G slabs; chain fused, x_in in registers.

struct RnnArgs {
  const u16* Wb;
  u16* h0b;
  u16* h1b;
  u16* Gp;
  const float* xin;
  const float* brec;
  u32* bar;
};

__global__ __launch_bounds__(512, 1) void k_rnn(RnnArgs args) {
  extern __shared__ u16 smem[];
  u16* Wl = smem;            // 65536 elems = 128 KB
  u16* Al = smem + 65536;    // 2 x 8192 elems = 32 KB

  int bid = blockIdx.x;
  int l = bid & 3;
  int ks = (bid >> 2) & 3;
  int nt = bid >> 4;

  int tid = threadIdx.x;
  int w = tid >> 6, lane = tid & 63;
  int l15 = lane & 15, l4 = lane >> 4;
  int wr = w >> 1, wc = w & 1;  // 4M x 2N waves, wave tile 64x64

  // ---- load W slice into LDS (once) ----
  {
    const u16* Wg = args.Wb + (size_t)l * (NH * NH) + ks * 512;
    #pragma unroll
    for (int i = 0; i < 16; i++) {
      int r = i * 8 + w;                 // wave-uniform row
      int csw = lane ^ (r & 7);          // per-lane inverse-swizzled chunk
      gload16(Wg + (size_t)(nt * 128 + r) * NH + csw * 8,
              Wl + (size_t)(i * 512 + w * 64) * 8);
    }
  }
  WAITVM(0);
  __builtin_amdgcn_s_barrier();

  // chain assignment: 4 consecutive elems of (B x NH)
  int gid = bid * 512 + tid;
  int e = gid * 4;
  int col = e & (NH - 1);
  f32x4 p0 = *(const f32x4*)(args.xin + e);  // register-resident x_in

  u16* Go = args.Gp + (size_t)(ks * LAY + l) * (BATCH * NH) + nt * 128;
  u32 ep = 0;

  auto stageA = [&](const u16* Ag, int bufi, int kb) {
    int k0 = kb * 32;
    #pragma unroll
    for (int j = 0; j < 2; j++) {
      int r = j * 128 + w * 16 + (lane >> 2);
      int csw = (lane & 3) ^ (r & 3);
      gload16(Ag + (size_t)r * NH + k0 + csw * 8,
              Al + (size_t)bufi * 8192 + (size_t)(j * 512 + w * 64) * 8);
    }
  };

  for (int t = 0; t < TSS; t++) {
    if (t > 0) {
      const u16* Ag = ((t & 1) ? args.h1b : args.h0b) +
                      (size_t)l * (BATCH * NH) + ks * 512;

      f32x4 zero = {0.f, 0.f, 0.f, 0.f};
      f32x4 acc[4][4];
      #pragma unroll
      for (int m = 0; m < 4; m++)
        #pragma unroll
        for (int n = 0; n < 4; n++) acc[m][n] = zero;

      auto compute = [&](int bufi, int kb) {
        bf16x8 a[4], b[4];
        #pragma unroll
        for (int m = 0; m < 4; m++) {
          int row = wr * 64 + m * 16 + l15;
          a[m] = ld_frag(Al + bufi * 8192 + row * 32 + ((l4 ^ (row & 3)) * 8));
        }
        #pragma unroll
        for (int n = 0; n < 4; n++) {
          int row = wc * 64 + n * 16 + l15;
          int c = kb * 4 + l4;
          b[n] = ld_frag(Wl + row * 512 + ((c ^ (row & 7)) * 8));
        }
        #pragma unroll
        for (int m = 0; m < 4; m++)
          #pragma unroll
          for (int n = 0; n < 4; n++)
            acc[m][n] = mfma16(a[m], b[n], acc[m][n]);
      };

      stageA(Ag, 0, 0);
      stageA(Ag, 1, 1);
      int cur = 0;
      #pragma unroll 1
      for (int kb = 0; kb < 14; kb++) {
        WAITVM(2);
        __builtin_amdgcn_s_barrier();
        compute(cur, kb);
        __builtin_amdgcn_s_barrier();
        stageA(Ag, cur, kb + 2);
        cur ^= 1;
      }
      WAITVM(2);
      __builtin_amdgcn_s_barrier();
      compute(cur, 14);
      cur ^= 1;
      WAITVM(0);
      __builtin_amdgcn_s_barrier();
      compute(cur, 15);

      #pragma unroll
      for (int m = 0; m < 4; m++) {
        int row = wr * 64 + m * 16 + l4 * 4;
        #pragma unroll
        for (int n = 0; n < 4; n++) {
          int cc = wc * 64 + n * 16 + l15;
          #pragma unroll
          for (int r = 0; r < 4; r++)
            Go[(size_t)(row + r) * NH + cc] = f2bf(acc[m][n][r]);
        }
      }
      gbar(args.bar, ++ep);
    }

    // ---- chain phase (r5 4-partial sum order) ----
    u16* hout = (t & 1) ? args.h0b : args.h1b;
    f32x4 pre = p0;
    if (t == 0) {
      #pragma unroll
      for (int lc = 0; lc < LAY; lc++) {
        f32x4 bb = *(const f32x4*)(args.brec + lc * NH + col);
        u16x4 hv;
        #pragma unroll
        for (int j = 0; j < 4; j++) {
          float v = fast_sin(pre[j] + bb[j]);
          pre[j] = v;
          hv[j] = f2bf(v);
        }
        *(u16x4*)(hout + (size_t)lc * (BATCH * NH) + e) = hv;
      }
    } else {
      #pragma unroll
      for (int lc = 0; lc < LAY; lc++) {
        u16x4 g0 = *(const u16x4*)(args.Gp + (size_t)(0 * LAY + lc) * (BATCH * NH) + e);
        u16x4 g1 = *(const u16x4*)(args.Gp + (size_t)(1 * LAY + lc) * (BATCH * NH) + e);
        u16x4 g2 = *(const u16x4*)(args.Gp + (size_t)(2 * LAY + lc) * (BATCH * NH) + e);
        u16x4 g3 = *(const u16x4*)(args.Gp + (size_t)(3 * LAY + lc) * (BATCH * NH) + e);
        f32x4 bb = *(const f32x4*)(args.brec + lc * NH + col);
        u16x4 hv;
        #pragma unroll
        for (int j = 0; j < 4; j++) {
          float gs = (bf2f(g0[j]) + bf2f(g1[j])) + (bf2f(g2[j]) + bf2f(g3[j]));
          float v = fast_sin(pre[j] + gs + bb[j]);
          pre[j] = v;
          hv[j] = f2bf(v);
        }
        *(u16x4*)(hout + (size_t)lc * (BATCH * NH) + e) = hv;
      }
    }
    if (t + 1 < TSS) gbar(args.bar, ++ep);
  }
}

// ---------------- fallback chain (4 partials, r5-proven) --------------------
__global__ __launch_bounds__(256) void k_chain(const u16* __restrict__ Gp,
                                               const float* __restrict__ x_in,
                                               const float* __restrict__ brec,
                                               u16* __restrict__ hout) {
  int i = blockIdx.x * 256 + threadIdx.x;
  int e = i * 4;
  int col = e & (NH - 1);
  f32x4 pre = *(const f32x4*)(x_in + e);
  #pragma unroll
  for (int l = 0; l < LAY; l++) {
    u16x4 g0 = *(const u16x4*)(Gp + (size_t)(0 * LAY + l) * (BATCH * NH) + e);
    u16x4 g1 = *(const u16x4*)(Gp + (size_t)(1 * LAY + l) * (BATCH * NH) + e);
    u16x4 g2 = *(const u16x4*)(Gp + (size_t)(2 * LAY + l) * (BATCH * NH) + e);
    u16x4 g3 = *(const u16x4*)(Gp + (size_t)(3 * LAY + l) * (BATCH * NH) + e);
    f32x4 bb = *(const f32x4*)(brec + l * NH + col);
    u16x4 hv;
    #pragma unroll
    for (int j = 0; j < 4; j++) {
      float v = fast_sin(pre[j] + (bf2f(g0[j]) + bf2f(g1[j])) +
                         (bf2f(g2[j]) + bf2f(g3[j])) + bb[j]);
      pre[j] = v;
      hv[j] = f2bf(v);
    }
    *(u16x4*)(hout + (size_t)l * (BATCH * NH) + e) = hv;
  }
}

// x_in = sum of 6 partial slices + bias (fp32 partials)
__global__ __launch_bounds__(256) void k_xin_fin(const float* __restrict__ Gp2,
                                                 const float* __restrict__ bin,
                                                 float* __restrict__ x_in) {
  int i = blockIdx.x * 256 + threadIdx.x;
  int e = i * 4;
  int col = e & (NH - 1);
  f32x4 s = *(const f32x4*)(bin + col);
  #pragma unroll
  for (int t = 0; t < 6; t++)
    s += *(const f32x4*)(Gp2 + (size_t)t * (BATCH * NH) + e);
  *(f32x4*)(x_in + e) = s;
}

// ---------------- output projection: out = h3 @ (Wh+Wl)^T + b ----------------
__global__ __launch_bounds__(64) void k_gemm_out(const u16* __restrict__ h3,
                                                 const u16* __restrict__ Wh,
                                                 const u16* __restrict__ Wl,
                                                 const float* __restrict__ bout,
                                                 float* __restrict__ out) {
  int bid = blockIdx.x;  // 128 = 8 mt x 16 nt
  int mt = bid & 7, nt = bid >> 3;
  int lane = threadIdx.x;
  int l15 = lane & 15, l4 = lane >> 4;
  f32x4 zero = {0.f, 0.f, 0.f, 0.f};
  f32x4 acc0 = zero, acc1 = zero;
  const u16* a0p = h3 + (size_t)(mt * 32 + l15) * NH + l4 * 8;
  const u16* a1p = a0p + 16 * NH;
  const u16* bhp = Wh + (size_t)(nt * 16 + l15) * NH + l4 * 8;
  const u16* blp = Wl + (size_t)(nt * 16 + l15) * NH + l4 * 8;
  for (int kb = 0; kb < 64; kb++) {
    bf16x8 a0 = ld_frag(a0p + kb * 32);
    bf16x8 a1 = ld_frag(a1p + kb * 32);
    bf16x8 bh = ld_frag(bhp + kb * 32);
    bf16x8 bl = ld_frag(blp + kb * 32);
    acc0 = mfma16(a0, bh, acc0);
    acc0 = mfma16(a0, bl, acc0);
    acc1 = mfma16(a1, bh, acc1);
    acc1 = mfma16(a1, bl, acc1);
  }
  float bo = bout[nt * 16 + l15];
  #pragma unroll
  for (int r = 0; r < 4; r++) {
    out[(size_t)(mt * 32 + l4 * 4 + r) * NOUT + nt * 16 + l15] = acc0[r] + bo;
    out[(size_t)(mt * 32 + 16 + l4 * 4 + r) * NOUT + nt * 16 + l15] = acc1[r] + bo;
  }
}

// ---------------- host ----------------

extern "C" void kernel_launch(void* const* d_in, const int* in_sizes, int n_in,
                              void* d_out, int out_size, void* d_ws, size_t ws_size,
                              hipStream_t stream) {
  const float* X     = (const float*)d_in[0];
  const float* Winw  = (const float*)d_in[1];
  const float* Winb  = (const float*)d_in[2];
  const float* Wrw   = (const float*)d_in[3];
  const float* Wrb   = (const float*)d_in[4];
  const float* Woutw = (const float*)d_in[5];
  const float* Woutb = (const float*)d_in[6];
  float* out = (float*)d_out;

  char* ws = (char*)d_ws;
  u16* Wb     = (u16*)(ws);                    // 32 MB  bf16 W_rec
  u16* h0     = (u16*)(ws + 33554432);         // 4 MB
  u16* h1     = (u16*)(ws + 37748736);         // 4 MB
  float* xin  = (float*)(ws + 41943040);       // 2 MB
  u16* Gp     = (u16*)(ws + 44040192);         // 16 MB bf16 (4 ks x 4 l)
  float* Gp2  = (float*)(ws + 60817408);       // 12 MB fp32 (2 ks x 3 terms)
  u16* Xhi    = (u16*)(ws + 73400320);         // 512 KB
  u16* Xlo    = (u16*)(ws + 73924608);         // 512 KB
  u16* Winh   = (u16*)(ws + 74448896);         // 4 MB
  u16* Winl   = (u16*)(ws + 78643200);         // 4 MB
  u16* Wouth  = (u16*)(ws + 82837504);         // 1 MB
  u16* Woutl  = (u16*)(ws + 83886080);         // 1 MB
  u32* bar    = (u32*)(ws + 84934656);         // 256 B barrier counter

  // pack weights (every call; stateless)
  k_cvt<<<16384, 256, 0, stream>>>(Wrw, Wb, 4194304);
  k_split2<<<256, 256, 0, stream>>>(X, Xhi, Xlo, 65536);
  k_split2<<<2048, 256, 0, stream>>>(Winw, Winh, Winl, 524288);
  k_split2<<<512, 256, 0, stream>>>(Woutw, Wouth, Woutl, 131072);

  // x_in = X @ W_in^T (+bias), 3-term bf16 split, fp32 partials, split-K 2
  GemmArgs ax;
  ax.A[0] = Xhi; ax.A[1] = Xhi; ax.A[2] = Xlo; ax.A[3] = Xhi;
  ax.B[0] = Winh; ax.B[1] = Winl; ax.B[2] = Winh; ax.B[3] = Winh;
  ax.G = Gp2; ax.ldA = NIN; ax.ldB = NIN; ax.kiters = 8; ax.nl = 3;
  k_gemm<0, 2><<<192, 256, 0, stream>>>(ax);
  k_xin_fin<<<512, 256, 0, stream>>>(Gp2, Winb, xin);

  // persistent W-resident kernel (manual grid barrier; plain launch)
  hipError_t e1 = hipFuncSetAttribute(
      (const void*)k_rnn, hipFuncAttributeMaxDynamicSharedMemorySize, 163840);
  bool persist = (e1 == hipSuccess);
  if (persist) {
    hipMemsetAsync(bar, 0, 256, stream);
    RnnArgs ra;
    ra.Wb = Wb; ra.h0b = h0; ra.h1b = h1; ra.Gp = Gp;
    ra.xin = xin; ra.brec = Wrb; ra.bar = bar;
    k_rnn<<<dim3(256), dim3(512), 163840, stream>>>(ra);
    persist = (hipGetLastError() == hipSuccess);
  }
  if (!persist) {
    // deterministic fallback: r5 separate-kernel loop (same numerics)
    hipMemsetAsync(h0, 0, 4194304, stream);
    u16* hin = h0;
    u16* hout = h1;
    for (int t = 0; t < TSS; t++) {
      GemmArgs ar;
      for (int l = 0; l < 4; l++) {
        ar.A[l] = hin + (size_t)l * (BATCH * NH);
        ar.B[l] = Wb + (size_t)l * (NH * NH);
      }
      ar.G = Gp; ar.ldA = NH; ar.ldB = NH; ar.kiters = 8; ar.nl = 4;
      k_gemm<1, 4><<<512, 256, 0, stream>>>(ar);
      k_chain<<<512, 256, 0, stream>>>(Gp, xin, Wrb, hout);
      u16* tmp = hin; hin = hout; hout = tmp;
    }
  }

  // final layer-3 hidden state lives in h0 (both paths); output projection
  k_gemm_out<<<128, 64, 0, stream>>>(h0 + (size_t)3 * (BATCH * NH), Wouth, Woutl,
                                     Woutb, out);
}

// Round 13
// 662.120 us; speedup vs baseline: 11.4307x; 7.8699x over previous
//
#include <hip/hip_runtime.h>

typedef unsigned short u16;
typedef unsigned char u8;
typedef unsigned int u32;
typedef __bf16 bf16x8 __attribute__((ext_vector_type(8)));
typedef float f32x4 __attribute__((ext_vector_type(4)));
typedef u32 u32x4 __attribute__((ext_vector_type(4)));
typedef u16 u16x4 __attribute__((ext_vector_type(4)));
typedef int i32x4 __attribute__((ext_vector_type(4)));

#define NH 2048
#define BATCH 256
#define NIN 1024
#define NOUT 256
#define LAY 4
#define TSS 32
#define BK 64

#define SW_W 5747.0f  // 127 / (1/sqrt(2048)); |W|<0.0220971 -> |W*SW_W|<127.002
#define INV_DQ (1.0f / (127.0f * 5747.0f))

#define WAITVM(N) asm volatile("s_waitcnt vmcnt(" #N ")" ::: "memory")

__device__ __forceinline__ u16 f2bf(float f) {
  u32 u = __builtin_bit_cast(u32, f);
  u = (u + 0x7FFFu + ((u >> 16) & 1u)) >> 16;
  return (u16)u;
}
__device__ __forceinline__ float bf2f(u16 h) {
  u32 u = ((u32)h) << 16;
  return __builtin_bit_cast(float, u);
}

// sin for |x| <= ~6, abs err < ~4e-6 (degree-9 odd, pi range reduction)
__device__ __forceinline__ float fast_sin(float x) {
  float k = __builtin_rintf(x * 0.3183098861837907f);
  float r = __builtin_fmaf(k, -3.14159274101257324f, x);
  r = __builtin_fmaf(k, 8.742277657347586e-08f, r);
  float s = r * r;
  float p = __builtin_fmaf(s, 2.75573192e-06f, -1.98412698e-04f);
  p = __builtin_fmaf(s, p, 8.33333333e-03f);
  p = __builtin_fmaf(s, p, -1.66666667e-01f);
  p = r + r * s * p;
  int ki = (int)k;
  return (ki & 1) ? -p : p;
}

__device__ __forceinline__ bf16x8 ld_frag(const u16* p) {
  u32x4 r = *(const u32x4*)p;
  return __builtin_bit_cast(bf16x8, r);
}

__device__ __forceinline__ f32x4 mfma16(bf16x8 a, bf16x8 b, f32x4 c) {
  return __builtin_amdgcn_mfma_f32_16x16x32_bf16(a, b, c, 0, 0, 0);
}

// i8 MFMA via the documented gfx950 builtin (compiler handles all hazards)
__device__ __forceinline__ i32x4 mfma_i8(i32x4 a, i32x4 b, i32x4 c) {
  return __builtin_amdgcn_mfma_i32_16x16x64_i8(a, b, c, 0, 0, 0);
}

__device__ __forceinline__ void gload16(const void* g, void* lds) {
  __builtin_amdgcn_global_load_lds(
      (__attribute__((address_space(1))) u32*)g,
      (__attribute__((address_space(3))) u32*)lds, 16, 0, 0);
}

// ---------------- pack / convert kernels ----------------

// W fp32 -> i8 (scale SW_W), 4 elems/thread
__global__ __launch_bounds__(256) void k_cvt_w8(const float* __restrict__ in,
                                                u32* __restrict__ out, int n4) {
  int i = blockIdx.x * 256 + threadIdx.x;
  if (i >= n4) return;
  f32x4 v = ((const f32x4*)in)[i];
  u32 o = 0;
  #pragma unroll
  for (int j = 0; j < 4; j++) {
    int q = (int)__builtin_rintf(v[j] * SW_W);
    o |= ((u32)(q & 255)) << (8 * j);
  }
  out[i] = o;
}

__global__ __launch_bounds__(256) void k_split2(const float* __restrict__ in,
                                                u16* __restrict__ hi,
                                                u16* __restrict__ lo, int n4) {
  int i = blockIdx.x * 256 + threadIdx.x;
  if (i >= n4) return;
  f32x4 v = ((const f32x4*)in)[i];
  u16x4 hv, lv;
  #pragma unroll
  for (int j = 0; j < 4; j++) {
    u16 h = f2bf(v[j]);
    hv[j] = h;
    lv[j] = f2bf(v[j] - bf2f(h));
  }
  ((u16x4*)hi)[i] = hv;
  ((u16x4*)lo)[i] = lv;
}

// ---------------- bf16 GEMM (r5-proven 2-phase structure; x_in path) --------

struct GemmArgs {
  const u16* A[4];
  const u16* B[4];
  void* G;
  int ldA, ldB, kiters, nl;
};

template <int OBF, int NKS>
__global__ __launch_bounds__(256, 2) void k_gemm(GemmArgs args) {
  __shared__ alignas(16) u16 Ab[2][128 * BK];
  __shared__ alignas(16) u16 Bb[2][128 * BK];

  int bid = blockIdx.x;
  int nl = args.nl;
  int l = bid % nl;
  int t1 = bid / nl;
  int ks = t1 & (NKS - 1);
  int t2 = t1 / NKS;
  int nt = t2 & 15;
  int mt = t2 >> 4;

  int tid = threadIdx.x;
  int w = tid >> 6, lane = tid & 63;
  int l15 = lane & 15, l4 = lane >> 4;
  int ldA = args.ldA, ldB = args.ldB;
  int kiters = args.kiters;

  const u16* Ag = args.A[l] + (size_t)(mt * 128) * ldA + ks * (kiters * BK);
  const u16* Bg = args.B[l] + (size_t)(nt * 128) * ldB + ks * (kiters * BK);

  int srow = w * 32 + (lane >> 3);
  int csrc = ((lane & 7) ^ (lane >> 3)) * 8;
  int agoff[4], bgoff[4], lbase[4];
  #pragma unroll
  for (int j = 0; j < 4; j++) {
    agoff[j] = (srow + j * 8) * ldA + csrc;
    bgoff[j] = (srow + j * 8) * ldB + csrc;
    lbase[j] = w * 2048 + j * 512;
  }

  int wr = w >> 1, wc = w & 1;

  f32x4 zero = {0.f, 0.f, 0.f, 0.f};
  f32x4 acc[4][4];
  #pragma unroll
  for (int m = 0; m < 4; m++)
    #pragma unroll
    for (int n = 0; n < 4; n++) acc[m][n] = zero;

  auto stage = [&](int bufi, int kb) {
    int k0 = kb * BK;
    #pragma unroll
    for (int j = 0; j < 4; j++) {
      gload16(Ag + agoff[j] + k0, &Ab[bufi][lbase[j]]);
      gload16(Bg + bgoff[j] + k0, &Bb[bufi][lbase[j]]);
    }
  };
  auto compute = [&](int bufi) {
    #pragma unroll
    for (int kk = 0; kk < 2; kk++) {
      int swz = ((kk * 4 + l4) ^ (l15 & 7)) * 8;
      bf16x8 a[4], b[4];
      #pragma unroll
      for (int m = 0; m < 4; m++)
        a[m] = ld_frag(&Ab[bufi][(wr * 64 + m * 16 + l15) * BK + swz]);
      #pragma unroll
      for (int n = 0; n < 4; n++)
        b[n] = ld_frag(&Bb[bufi][(wc * 64 + n * 16 + l15) * BK + swz]);
      #pragma unroll
      for (int m = 0; m < 4; m++)
        #pragma unroll
        for (int n = 0; n < 4; n++)
          acc[m][n] = mfma16(a[m], b[n], acc[m][n]);
    }
  };

  stage(0, 0);
  stage(1, 1);

  int cur = 0;
  for (int kb = 0; kb < kiters - 2; kb++) {
    WAITVM(8);
    __builtin_amdgcn_s_barrier();
    compute(cur);
    __builtin_amdgcn_s_barrier();
    stage(cur, kb + 2);
    cur ^= 1;
  }
  WAITVM(8);
  __builtin_amdgcn_s_barrier();
  compute(cur);
  cur ^= 1;
  WAITVM(0);
  __builtin_amdgcn_s_barrier();
  compute(cur);

  size_t obase = ((size_t)(ks * nl + l) * BATCH + mt * 128) * NH + nt * 128;
  if (OBF) {
    u16* Go = (u16*)args.G + obase;
    #pragma unroll
    for (int m = 0; m < 4; m++) {
      int row = wr * 64 + m * 16 + l4 * 4;
      #pragma unroll
      for (int n = 0; n < 4; n++) {
        int col = wc * 64 + n * 16 + l15;
        #pragma unroll
        for (int r = 0; r < 4; r++)
          Go[(size_t)(row + r) * NH + col] = f2bf(acc[m][n][r]);
      }
    }
  } else {
    float* Go = (float*)args.G + obase;
    #pragma unroll
    for (int m = 0; m < 4; m++) {
      int row = wr * 64 + m * 16 + l4 * 4;
      #pragma unroll
      for (int n = 0; n < 4; n++) {
        int col = wc * 64 + n * 16 + l15;
        #pragma unroll
        for (int r = 0; r < 4; r++)
          Go[(size_t)(row + r) * NH + col] = acc[m][n][r];
      }
    }
  }
}

// ---------------- recurrent GEMM, int8: 128x128 tile, BK=128 i8 -------------
// Byte-identical addressing to the r5-proven bf16 kernel: LDS rows 128 B,
// XOR swizzle 16B-chunk ^= (row&7) on inverse-swizzled global source + reads
// (2-way bank aliasing = free). mfma_i32_16x16x64_i8 (builtin): per kk (K=64),
// lane reads 16 B at chunk (kk*4+l4)^(row&7) — direct analog of the bf16
// fragment (same 16 B/lane, row=l15, K-group=l4).
// kiters=4 (K-slice 512, ks=4), grid 512 = 2 blocks/CU, 2-barrier schedule.
// Epilogue dequant: G = acc_i32 * 1/(127*5747) -> bf16.
// Decode: l=bid&3, ks=(bid>>2)&3, nt=(bid>>4)&15, mt=bid>>8.

struct Rec8Args {
  const u8* h;    // [LAY][BATCH][NH] i8
  const u8* W8;   // [LAY][NH][NH] i8
  u16* Gp;        // 16 slabs [ks*LAY+l][BATCH][NH] bf16
};

__global__ __launch_bounds__(256, 2) void k_gemm8(Rec8Args args) {
  __shared__ alignas(16) u8 Ab[2][128 * 128];
  __shared__ alignas(16) u8 Bb[2][128 * 128];

  int bid = blockIdx.x;
  int l = bid & 3;
  int ks = (bid >> 2) & 3;
  int nt = (bid >> 4) & 15;
  int mt = bid >> 8;

  int tid = threadIdx.x;
  int lane = tid & 63;
  int w = tid >> 6;
  int l15 = lane & 15, l4 = lane >> 4;
  int wr = w >> 1, wc = w & 1;

  const u8* Ag = args.h + (size_t)l * (BATCH * NH) + (size_t)(mt * 128) * NH + ks * 512;
  const u8* Bg = args.W8 + (size_t)l * (NH * NH) + (size_t)(nt * 128) * NH + ks * 512;

  // staging: LDS linear byte L = j*4096 + tid*16 -> row = j*32 + (tid>>3),
  // chunkpos = tid&7; inverse-swizzled source chunk = chunkpos ^ (row&7).
  int srow = tid >> 3;
  int csrc = ((tid & 7) ^ (srow & 7)) * 16;  // bytes
  int goff[4], lbase[4];
  #pragma unroll
  for (int j = 0; j < 4; j++) {
    goff[j] = (j * 32 + srow) * NH + csrc;
    lbase[j] = j * 4096 + tid * 16;
  }

  i32x4 zero = {0, 0, 0, 0};
  i32x4 acc[4][4];
  #pragma unroll
  for (int m = 0; m < 4; m++)
    #pragma unroll
    for (int n = 0; n < 4; n++) acc[m][n] = zero;

  auto stage = [&](int bufi, int kb) {
    int k0 = kb * 128;
    #pragma unroll
    for (int j = 0; j < 4; j++) {
      gload16(Ag + goff[j] + k0, &Ab[bufi][lbase[j]]);
      gload16(Bg + goff[j] + k0, &Bb[bufi][lbase[j]]);
    }
  };
  auto compute = [&](int bufi) {
    #pragma unroll
    for (int kk = 0; kk < 2; kk++) {
      int swz = ((kk * 4 + l4) ^ (l15 & 7)) * 16;  // bytes
      i32x4 a[4], b[4];
      #pragma unroll
      for (int m = 0; m < 4; m++)
        a[m] = *(const i32x4*)&Ab[bufi][(wr * 64 + m * 16 + l15) * 128 + swz];
      #pragma unroll
      for (int n = 0; n < 4; n++)
        b[n] = *(const i32x4*)&Bb[bufi][(wc * 64 + n * 16 + l15) * 128 + swz];
      #pragma unroll
      for (int m = 0; m < 4; m++)
        #pragma unroll
        for (int n = 0; n < 4; n++)
          acc[m][n] = mfma_i8(a[m], b[n], acc[m][n]);
    }
  };

  stage(0, 0);
  stage(1, 1);

  int cur = 0;
  #pragma unroll 1
  for (int kb = 0; kb < 2; kb++) {  // kiters = 4
    WAITVM(8);
    __builtin_amdgcn_s_barrier();
    compute(cur);
    __builtin_amdgcn_s_barrier();
    stage(cur, kb + 2);
    cur ^= 1;
  }
  WAITVM(8);
  __builtin_amdgcn_s_barrier();
  compute(cur);
  cur ^= 1;
  WAITVM(0);
  __builtin_amdgcn_s_barrier();
  compute(cur);

  u16* Go = args.Gp + (size_t)(ks * LAY + l) * (BATCH * NH) +
            (size_t)(mt * 128) * NH + nt * 128;
  #pragma unroll
  for (int m = 0; m < 4; m++) {
    int row = wr * 64 + m * 16 + l4 * 4;
    #pragma unroll
    for (int n = 0; n < 4; n++) {
      int col = wc * 64 + n * 16 + l15;
      #pragma unroll
      for (int r = 0; r < 4; r++)
        Go[(size_t)(row + r) * NH + col] = f2bf((float)acc[m][n][r] * INV_DQ);
    }
  }
}

// ---------------- sin chain: bf16 G partials in, i8 h out (+bf16 h3) --------
__global__ __launch_bounds__(256) void k_chain8(const u16* __restrict__ Gp,
                                                const float* __restrict__ x_in,
                                                const float* __restrict__ brec,
                                                u8* __restrict__ hq,
                                                u16* __restrict__ h3bf) {
  int i = blockIdx.x * 256 + threadIdx.x;  // 131072 threads, 4 elems each
  int e = i * 4;
  int col = e & (NH - 1);
  f32x4 pre = *(const f32x4*)(x_in + e);
  #pragma unroll
  for (int l = 0; l < LAY; l++) {
    u16x4 g0 = *(const u16x4*)(Gp + (size_t)(0 * LAY + l) * (BATCH * NH) + e);
    u16x4 g1 = *(const u16x4*)(Gp + (size_t)(1 * LAY + l) * (BATCH * NH) + e);
    u16x4 g2 = *(const u16x4*)(Gp + (size_t)(2 * LAY + l) * (BATCH * NH) + e);
    u16x4 g3 = *(const u16x4*)(Gp + (size_t)(3 * LAY + l) * (BATCH * NH) + e);
    f32x4 bb = *(const f32x4*)(brec + l * NH + col);
    u32 qw = 0;
    u16x4 hv;
    #pragma unroll
    for (int j = 0; j < 4; j++) {
      float v = fast_sin(pre[j] + (bf2f(g0[j]) + bf2f(g1[j])) +
                         (bf2f(g2[j]) + bf2f(g3[j])) + bb[j]);
      pre[j] = v;
      int q = (int)__builtin_rintf(v * 127.0f);
      qw |= ((u32)(q & 255)) << (8 * j);
      hv[j] = f2bf(v);
    }
    *(u32*)(hq + (size_t)l * (BATCH * NH) + e) = qw;
    if (l == LAY - 1) *(u16x4*)(h3bf + e) = hv;
  }
}

// x_in = sum of 6 partial slices + bias (fp32 partials)
__global__ __launch_bounds__(256) void k_xin_fin(const float* __restrict__ Gp2,
                                                 const float* __restrict__ bin,
                                                 float* __restrict__ x_in) {
  int i = blockIdx.x * 256 + threadIdx.x;
  int e = i * 4;
  int col = e & (NH - 1);
  f32x4 s = *(const f32x4*)(bin + col);
  #pragma unroll
  for (int t = 0; t < 6; t++)
    s += *(const f32x4*)(Gp2 + (size_t)t * (BATCH * NH) + e);
  *(f32x4*)(x_in + e) = s;
}

// ---------------- output projection: out = h3 @ (Wh+Wl)^T + b ----------------
__global__ __launch_bounds__(64) void k_gemm_out(const u16* __restrict__ h3,
                                                 const u16* __restrict__ Wh,
                                                 const u16* __restrict__ Wl,
                                                 const float* __restrict__ bout,
                                                 float* __restrict__ out) {
  int bid = blockIdx.x;  // 128 = 8 mt x 16 nt
  int mt = bid & 7, nt = bid >> 3;
  int lane = threadIdx.x;
  int l15 = lane & 15, l4 = lane >> 4;
  f32x4 zero = {0.f, 0.f, 0.f, 0.f};
  f32x4 acc0 = zero, acc1 = zero;
  const u16* a0p = h3 + (size_t)(mt * 32 + l15) * NH + l4 * 8;
  const u16* a1p = a0p + 16 * NH;
  const u16* bhp = Wh + (size_t)(nt * 16 + l15) * NH + l4 * 8;
  const u16* blp = Wl + (size_t)(nt * 16 + l15) * NH + l4 * 8;
  for (int kb = 0; kb < 64; kb++) {
    bf16x8 a0 = ld_frag(a0p + kb * 32);
    bf16x8 a1 = ld_frag(a1p + kb * 32);
    bf16x8 bh = ld_frag(bhp + kb * 32);
    bf16x8 bl = ld_frag(blp + kb * 32);
    acc0 = mfma16(a0, bh, acc0);
    acc0 = mfma16(a0, bl, acc0);
    acc1 = mfma16(a1, bh, acc1);
    acc1 = mfma16(a1, bl, acc1);
  }
  float bo = bout[nt * 16 + l15];
  #pragma unroll
  for (int r = 0; r < 4; r++) {
    out[(size_t)(mt * 32 + l4 * 4 + r) * NOUT + nt * 16 + l15] = acc0[r] + bo;
    out[(size_t)(mt * 32 + 16 + l4 * 4 + r) * NOUT + nt * 16 + l15] = acc1[r] + bo;
  }
}

// ---------------- host ----------------

extern "C" void kernel_launch(void* const* d_in, const int* in_sizes, int n_in,
                              void* d_out, int out_size, void* d_ws, size_t ws_size,
                              hipStream_t stream) {
  const float* X     = (const float*)d_in[0];
  const float* Winw  = (const float*)d_in[1];
  const float* Winb  = (const float*)d_in[2];
  const float* Wrw   = (const float*)d_in[3];
  const float* Wrb   = (const float*)d_in[4];
  const float* Woutw = (const float*)d_in[5];
  const float* Woutb = (const float*)d_in[6];
  float* out = (float*)d_out;

  char* ws = (char*)d_ws;
  u8*  W8     = (u8*)(ws);                     // 16 MB  i8 W_rec
  u8*  h0i    = (u8*)(ws + 16777216);          // 2 MB   i8 h
  u8*  h1i    = (u8*)(ws + 18874368);          // 2 MB   i8 h
  u16* h3bf   = (u16*)(ws + 20971520);         // 1 MB   bf16 h layer-3
  float* xin  = (float*)(ws + 22020096);       // 2 MB
  u16* Gp     = (u16*)(ws + 24117248);         // 16 MB  bf16 (4 ks x 4 l)
  float* Gp2  = (float*)(ws + 40894464);       // 12 MB  fp32 (2 ks x 3 terms)
  u16* Xhi    = (u16*)(ws + 53477376);         // 512 KB
  u16* Xlo    = (u16*)(ws + 54001664);         // 512 KB
  u16* Winh   = (u16*)(ws + 54525952);         // 4 MB
  u16* Winl   = (u16*)(ws + 58720256);         // 4 MB
  u16* Wouth  = (u16*)(ws + 62914560);         // 1 MB
  u16* Woutl  = (u16*)(ws + 63963136);         // 1 MB -> end 65011712

  // pack weights (every call; stateless)
  k_cvt_w8<<<16384, 256, 0, stream>>>(Wrw, (u32*)W8, 4194304);
  k_split2<<<256, 256, 0, stream>>>(X, Xhi, Xlo, 65536);
  k_split2<<<2048, 256, 0, stream>>>(Winw, Winh, Winl, 524288);
  k_split2<<<512, 256, 0, stream>>>(Woutw, Wouth, Woutl, 131072);
  hipMemsetAsync(h0i, 0, 2097152, stream);

  // x_in = X @ W_in^T (+bias), 3-term bf16 split, fp32 partials, split-K 2
  GemmArgs ax;
  ax.A[0] = Xhi; ax.A[1] = Xhi; ax.A[2] = Xlo; ax.A[3] = Xhi;
  ax.B[0] = Winh; ax.B[1] = Winl; ax.B[2] = Winh; ax.B[3] = Winh;
  ax.G = Gp2; ax.ldA = NIN; ax.ldB = NIN; ax.kiters = 8; ax.nl = 3;
  k_gemm<0, 2><<<192, 256, 0, stream>>>(ax);
  k_xin_fin<<<512, 256, 0, stream>>>(Gp2, Winb, xin);

  u8* hin = h0i;
  u8* hout = h1i;
  for (int t = 0; t < TSS; t++) {
    Rec8Args ar;
    ar.h = hin; ar.W8 = W8; ar.Gp = Gp;
    k_gemm8<<<512, 256, 0, stream>>>(ar);
    k_chain8<<<512, 256, 0, stream>>>(Gp, xin, Wrb, hout, h3bf);
    u8* tmp = hin; hin = hout; hout = tmp;
  }

  // h3bf holds the final layer-3 hidden state (written by last k_chain8)
  k_gemm_out<<<128, 64, 0, stream>>>(h3bf, Wouth, Woutl, Woutb, out);
}

// Round 14
// 596.049 us; speedup vs baseline: 12.6978x; 1.1108x over previous
//
#include <hip/hip_runtime.h>

typedef unsigned short u16;
typedef unsigned char u8;
typedef unsigned int u32;
typedef __bf16 bf16x8 __attribute__((ext_vector_type(8)));
typedef float f32x4 __attribute__((ext_vector_type(4)));
typedef u32 u32x4 __attribute__((ext_vector_type(4)));
typedef u32 u32x2 __attribute__((ext_vector_type(2)));
typedef u16 u16x4 __attribute__((ext_vector_type(4)));
typedef u16 u16x8 __attribute__((ext_vector_type(8)));
typedef int i32x4 __attribute__((ext_vector_type(4)));

#define NH 2048
#define BATCH 256
#define NIN 1024
#define NOUT 256
#define LAY 4
#define TSS 32
#define BK 64

#define SW_W 5747.0f  // 127 / (1/sqrt(2048)); |W|<0.0220971 -> |W*SW_W|<127.002
#define INV_DQ (1.0f / (127.0f * 5747.0f))

#define WAITVM(N) asm volatile("s_waitcnt vmcnt(" #N ")" ::: "memory")

__device__ __forceinline__ u16 f2bf(float f) {
  u32 u = __builtin_bit_cast(u32, f);
  u = (u + 0x7FFFu + ((u >> 16) & 1u)) >> 16;
  return (u16)u;
}
__device__ __forceinline__ float bf2f(u16 h) {
  u32 u = ((u32)h) << 16;
  return __builtin_bit_cast(float, u);
}

// sin for |x| <= ~6, abs err < ~4e-6 (degree-9 odd, pi range reduction)
__device__ __forceinline__ float fast_sin(float x) {
  float k = __builtin_rintf(x * 0.3183098861837907f);
  float r = __builtin_fmaf(k, -3.14159274101257324f, x);
  r = __builtin_fmaf(k, 8.742277657347586e-08f, r);
  float s = r * r;
  float p = __builtin_fmaf(s, 2.75573192e-06f, -1.98412698e-04f);
  p = __builtin_fmaf(s, p, 8.33333333e-03f);
  p = __builtin_fmaf(s, p, -1.66666667e-01f);
  p = r + r * s * p;
  int ki = (int)k;
  return (ki & 1) ? -p : p;
}

__device__ __forceinline__ bf16x8 ld_frag(const u16* p) {
  u32x4 r = *(const u32x4*)p;
  return __builtin_bit_cast(bf16x8, r);
}

__device__ __forceinline__ f32x4 mfma16(bf16x8 a, bf16x8 b, f32x4 c) {
  return __builtin_amdgcn_mfma_f32_16x16x32_bf16(a, b, c, 0, 0, 0);
}

// i8 MFMA via the documented gfx950 builtin (compiler handles all hazards)
__device__ __forceinline__ i32x4 mfma_i8(i32x4 a, i32x4 b, i32x4 c) {
  return __builtin_amdgcn_mfma_i32_16x16x64_i8(a, b, c, 0, 0, 0);
}

__device__ __forceinline__ void gload16(const void* g, void* lds) {
  __builtin_amdgcn_global_load_lds(
      (__attribute__((address_space(1))) u32*)g,
      (__attribute__((address_space(3))) u32*)lds, 16, 0, 0);
}

// ---------------- pack / convert kernels ----------------

// W fp32 -> i8 (scale SW_W), 4 elems/thread
__global__ __launch_bounds__(256) void k_cvt_w8(const float* __restrict__ in,
                                                u32* __restrict__ out, int n4) {
  int i = blockIdx.x * 256 + threadIdx.x;
  if (i >= n4) return;
  f32x4 v = ((const f32x4*)in)[i];
  u32 o = 0;
  #pragma unroll
  for (int j = 0; j < 4; j++) {
    int q = (int)__builtin_rintf(v[j] * SW_W);
    o |= ((u32)(q & 255)) << (8 * j);
  }
  out[i] = o;
}

__global__ __launch_bounds__(256) void k_split2(const float* __restrict__ in,
                                                u16* __restrict__ hi,
                                                u16* __restrict__ lo, int n4) {
  int i = blockIdx.x * 256 + threadIdx.x;
  if (i >= n4) return;
  f32x4 v = ((const f32x4*)in)[i];
  u16x4 hv, lv;
  #pragma unroll
  for (int j = 0; j < 4; j++) {
    u16 h = f2bf(v[j]);
    hv[j] = h;
    lv[j] = f2bf(v[j] - bf2f(h));
  }
  ((u16x4*)hi)[i] = hv;
  ((u16x4*)lo)[i] = lv;
}

// ---------------- bf16 GEMM (r5-proven 2-phase structure; x_in path) --------

struct GemmArgs {
  const u16* A[4];
  const u16* B[4];
  void* G;
  int ldA, ldB, kiters, nl;
};

template <int OBF, int NKS>
__global__ __launch_bounds__(256, 2) void k_gemm(GemmArgs args) {
  __shared__ alignas(16) u16 Ab[2][128 * BK];
  __shared__ alignas(16) u16 Bb[2][128 * BK];

  int bid = blockIdx.x;
  int nl = args.nl;
  int l = bid % nl;
  int t1 = bid / nl;
  int ks = t1 & (NKS - 1);
  int t2 = t1 / NKS;
  int nt = t2 & 15;
  int mt = t2 >> 4;

  int tid = threadIdx.x;
  int w = tid >> 6, lane = tid & 63;
  int l15 = lane & 15, l4 = lane >> 4;
  int ldA = args.ldA, ldB = args.ldB;
  int kiters = args.kiters;

  const u16* Ag = args.A[l] + (size_t)(mt * 128) * ldA + ks * (kiters * BK);
  const u16* Bg = args.B[l] + (size_t)(nt * 128) * ldB + ks * (kiters * BK);

  int srow = w * 32 + (lane >> 3);
  int csrc = ((lane & 7) ^ (lane >> 3)) * 8;
  int agoff[4], bgoff[4], lbase[4];
  #pragma unroll
  for (int j = 0; j < 4; j++) {
    agoff[j] = (srow + j * 8) * ldA + csrc;
    bgoff[j] = (srow + j * 8) * ldB + csrc;
    lbase[j] = w * 2048 + j * 512;
  }

  int wr = w >> 1, wc = w & 1;

  f32x4 zero = {0.f, 0.f, 0.f, 0.f};
  f32x4 acc[4][4];
  #pragma unroll
  for (int m = 0; m < 4; m++)
    #pragma unroll
    for (int n = 0; n < 4; n++) acc[m][n] = zero;

  auto stage = [&](int bufi, int kb) {
    int k0 = kb * BK;
    #pragma unroll
    for (int j = 0; j < 4; j++) {
      gload16(Ag + agoff[j] + k0, &Ab[bufi][lbase[j]]);
      gload16(Bg + bgoff[j] + k0, &Bb[bufi][lbase[j]]);
    }
  };
  auto compute = [&](int bufi) {
    #pragma unroll
    for (int kk = 0; kk < 2; kk++) {
      int swz = ((kk * 4 + l4) ^ (l15 & 7)) * 8;
      bf16x8 a[4], b[4];
      #pragma unroll
      for (int m = 0; m < 4; m++)
        a[m] = ld_frag(&Ab[bufi][(wr * 64 + m * 16 + l15) * BK + swz]);
      #pragma unroll
      for (int n = 0; n < 4; n++)
        b[n] = ld_frag(&Bb[bufi][(wc * 64 + n * 16 + l15) * BK + swz]);
      #pragma unroll
      for (int m = 0; m < 4; m++)
        #pragma unroll
        for (int n = 0; n < 4; n++)
          acc[m][n] = mfma16(a[m], b[n], acc[m][n]);
    }
  };

  stage(0, 0);
  stage(1, 1);

  int cur = 0;
  for (int kb = 0; kb < kiters - 2; kb++) {
    WAITVM(8);
    __builtin_amdgcn_s_barrier();
    compute(cur);
    __builtin_amdgcn_s_barrier();
    stage(cur, kb + 2);
    cur ^= 1;
  }
  WAITVM(8);
  __builtin_amdgcn_s_barrier();
  compute(cur);
  cur ^= 1;
  WAITVM(0);
  __builtin_amdgcn_s_barrier();
  compute(cur);

  size_t obase = ((size_t)(ks * nl + l) * BATCH + mt * 128) * NH + nt * 128;
  if (OBF) {
    u16* Go = (u16*)args.G + obase;
    #pragma unroll
    for (int m = 0; m < 4; m++) {
      int row = wr * 64 + m * 16 + l4 * 4;
      #pragma unroll
      for (int n = 0; n < 4; n++) {
        int col = wc * 64 + n * 16 + l15;
        #pragma unroll
        for (int r = 0; r < 4; r++)
          Go[(size_t)(row + r) * NH + col] = f2bf(acc[m][n][r]);
      }
    }
  } else {
    float* Go = (float*)args.G + obase;
    #pragma unroll
    for (int m = 0; m < 4; m++) {
      int row = wr * 64 + m * 16 + l4 * 4;
      #pragma unroll
      for (int n = 0; n < 4; n++) {
        int col = wc * 64 + n * 16 + l15;
        #pragma unroll
        for (int r = 0; r < 4; r++)
          Go[(size_t)(row + r) * NH + col] = acc[m][n][r];
      }
    }
  }
}

// ---------------- recurrent GEMM, int8: 128x128 tile, BK=128 i8, ks=2 -------
// r13-proven addressing; ks=2 -> kiters=8 (tail-drain fraction 50%->25%),
// grid 256, 8 G slabs (1 MB each). Decode: l=bid&3, ks=(bid>>2)&1,
// nt=(bid>>3)&15, mt=bid>>7; bid%8 = l+4*ks -> each XCD's L2 holds its
// (l,ks) W slice (2 MB) + A slice (0.5 MB), 32 sharer blocks on-XCD.
// Epilogue dequant: G = acc_i32 * 1/(127*5747) -> bf16.

struct Rec8Args {
  const u8* h;    // [LAY][BATCH][NH] i8
  const u8* W8;   // [LAY][NH][NH] i8
  u16* Gp;        // 8 slabs [ks*LAY+l][BATCH][NH] bf16
};

__global__ __launch_bounds__(256, 2) void k_gemm8(Rec8Args args) {
  __shared__ alignas(16) u8 Ab[2][128 * 128];
  __shared__ alignas(16) u8 Bb[2][128 * 128];

  int bid = blockIdx.x;
  int l = bid & 3;
  int ks = (bid >> 2) & 1;
  int nt = (bid >> 3) & 15;
  int mt = bid >> 7;

  int tid = threadIdx.x;
  int lane = tid & 63;
  int w = tid >> 6;
  int l15 = lane & 15, l4 = lane >> 4;
  int wr = w >> 1, wc = w & 1;

  const u8* Ag = args.h + (size_t)l * (BATCH * NH) + (size_t)(mt * 128) * NH + ks * 1024;
  const u8* Bg = args.W8 + (size_t)l * (NH * NH) + (size_t)(nt * 128) * NH + ks * 1024;

  // staging: LDS linear byte L = j*4096 + tid*16 -> row = j*32 + (tid>>3),
  // chunkpos = tid&7; inverse-swizzled source chunk = chunkpos ^ (row&7).
  int srow = tid >> 3;
  int csrc = ((tid & 7) ^ (srow & 7)) * 16;  // bytes
  int goff[4], lbase[4];
  #pragma unroll
  for (int j = 0; j < 4; j++) {
    goff[j] = (j * 32 + srow) * NH + csrc;
    lbase[j] = j * 4096 + tid * 16;
  }

  i32x4 zero = {0, 0, 0, 0};
  i32x4 acc[4][4];
  #pragma unroll
  for (int m = 0; m < 4; m++)
    #pragma unroll
    for (int n = 0; n < 4; n++) acc[m][n] = zero;

  auto stage = [&](int bufi, int kb) {
    int k0 = kb * 128;
    #pragma unroll
    for (int j = 0; j < 4; j++) {
      gload16(Ag + goff[j] + k0, &Ab[bufi][lbase[j]]);
      gload16(Bg + goff[j] + k0, &Bb[bufi][lbase[j]]);
    }
  };
  auto compute = [&](int bufi) {
    #pragma unroll
    for (int kk = 0; kk < 2; kk++) {
      int swz = ((kk * 4 + l4) ^ (l15 & 7)) * 16;  // bytes
      i32x4 a[4], b[4];
      #pragma unroll
      for (int m = 0; m < 4; m++)
        a[m] = *(const i32x4*)&Ab[bufi][(wr * 64 + m * 16 + l15) * 128 + swz];
      #pragma unroll
      for (int n = 0; n < 4; n++)
        b[n] = *(const i32x4*)&Bb[bufi][(wc * 64 + n * 16 + l15) * 128 + swz];
      #pragma unroll
      for (int m = 0; m < 4; m++)
        #pragma unroll
        for (int n = 0; n < 4; n++)
          acc[m][n] = mfma_i8(a[m], b[n], acc[m][n]);
    }
  };

  stage(0, 0);
  stage(1, 1);

  int cur = 0;
  #pragma unroll 1
  for (int kb = 0; kb < 6; kb++) {  // kiters = 8
    WAITVM(8);
    __builtin_amdgcn_s_barrier();
    compute(cur);
    __builtin_amdgcn_s_barrier();
    stage(cur, kb + 2);
    cur ^= 1;
  }
  WAITVM(8);
  __builtin_amdgcn_s_barrier();
  compute(cur);
  cur ^= 1;
  WAITVM(0);
  __builtin_amdgcn_s_barrier();
  compute(cur);

  u16* Go = args.Gp + (size_t)(ks * LAY + l) * (BATCH * NH) +
            (size_t)(mt * 128) * NH + nt * 128;
  #pragma unroll
  for (int m = 0; m < 4; m++) {
    int row = wr * 64 + m * 16 + l4 * 4;
    #pragma unroll
    for (int n = 0; n < 4; n++) {
      int col = wc * 64 + n * 16 + l15;
      #pragma unroll
      for (int r = 0; r < 4; r++)
        Go[(size_t)(row + r) * NH + col] = f2bf((float)acc[m][n][r] * INV_DQ);
    }
  }
}

// ---------------- sin chain: 2 bf16 G partials, 8 elems/thread, 16B loads ---
__global__ __launch_bounds__(256) void k_chain8(const u16* __restrict__ Gp,
                                                const float* __restrict__ x_in,
                                                const float* __restrict__ brec,
                                                u8* __restrict__ hq,
                                                u16* __restrict__ h3bf) {
  int i = blockIdx.x * 256 + threadIdx.x;  // 65536 threads, 8 elems each
  int e = i * 8;
  int col = e & (NH - 1);
  f32x4 p0 = *(const f32x4*)(x_in + e);
  f32x4 p1 = *(const f32x4*)(x_in + e + 4);
  #pragma unroll
  for (int l = 0; l < LAY; l++) {
    u16x8 g0 = *(const u16x8*)(Gp + (size_t)(0 * LAY + l) * (BATCH * NH) + e);
    u16x8 g1 = *(const u16x8*)(Gp + (size_t)(1 * LAY + l) * (BATCH * NH) + e);
    f32x4 b0 = *(const f32x4*)(brec + l * NH + col);
    f32x4 b1 = *(const f32x4*)(brec + l * NH + col + 4);
    u32x2 qw = {0u, 0u};
    u16x8 hv;
    #pragma unroll
    for (int j = 0; j < 4; j++) {
      float v = fast_sin(p0[j] + bf2f(g0[j]) + bf2f(g1[j]) + b0[j]);
      p0[j] = v;
      int q = (int)__builtin_rintf(v * 127.0f);
      qw[0] |= ((u32)(q & 255)) << (8 * j);
      hv[j] = f2bf(v);
    }
    #pragma unroll
    for (int j = 0; j < 4; j++) {
      float v = fast_sin(p1[j] + bf2f(g0[4 + j]) + bf2f(g1[4 + j]) + b1[j]);
      p1[j] = v;
      int q = (int)__builtin_rintf(v * 127.0f);
      qw[1] |= ((u32)(q & 255)) << (8 * j);
      hv[4 + j] = f2bf(v);
    }
    *(u32x2*)(hq + (size_t)l * (BATCH * NH) + e) = qw;
    if (l == LAY - 1) *(u16x8*)(h3bf + e) = hv;
  }
}

// x_in = sum of 6 partial slices + bias (fp32 partials)
__global__ __launch_bounds__(256) void k_xin_fin(const float* __restrict__ Gp2,
                                                 const float* __restrict__ bin,
                                                 float* __restrict__ x_in) {
  int i = blockIdx.x * 256 + threadIdx.x;
  int e = i * 4;
  int col = e & (NH - 1);
  f32x4 s = *(const f32x4*)(bin + col);
  #pragma unroll
  for (int t = 0; t < 6; t++)
    s += *(const f32x4*)(Gp2 + (size_t)t * (BATCH * NH) + e);
  *(f32x4*)(x_in + e) = s;
}

// ---------------- output projection: out = h3 @ (Wh+Wl)^T + b ----------------
__global__ __launch_bounds__(64) void k_gemm_out(const u16* __restrict__ h3,
                                                 const u16* __restrict__ Wh,
                                                 const u16* __restrict__ Wl,
                                                 const float* __restrict__ bout,
                                                 float* __restrict__ out) {
  int bid = blockIdx.x;  // 128 = 8 mt x 16 nt
  int mt = bid & 7, nt = bid >> 3;
  int lane = threadIdx.x;
  int l15 = lane & 15, l4 = lane >> 4;
  f32x4 zero = {0.f, 0.f, 0.f, 0.f};
  f32x4 acc0 = zero, acc1 = zero;
  const u16* a0p = h3 + (size_t)(mt * 32 + l15) * NH + l4 * 8;
  const u16* a1p = a0p + 16 * NH;
  const u16* bhp = Wh + (size_t)(nt * 16 + l15) * NH + l4 * 8;
  const u16* blp = Wl + (size_t)(nt * 16 + l15) * NH + l4 * 8;
  for (int kb = 0; kb < 64; kb++) {
    bf16x8 a0 = ld_frag(a0p + kb * 32);
    bf16x8 a1 = ld_frag(a1p + kb * 32);
    bf16x8 bh = ld_frag(bhp + kb * 32);
    bf16x8 bl = ld_frag(blp + kb * 32);
    acc0 = mfma16(a0, bh, acc0);
    acc0 = mfma16(a0, bl, acc0);
    acc1 = mfma16(a1, bh, acc1);
    acc1 = mfma16(a1, bl, acc1);
  }
  float bo = bout[nt * 16 + l15];
  #pragma unroll
  for (int r = 0; r < 4; r++) {
    out[(size_t)(mt * 32 + l4 * 4 + r) * NOUT + nt * 16 + l15] = acc0[r] + bo;
    out[(size_t)(mt * 32 + 16 + l4 * 4 + r) * NOUT + nt * 16 + l15] = acc1[r] + bo;
  }
}

// ---------------- host ----------------

extern "C" void kernel_launch(void* const* d_in, const int* in_sizes, int n_in,
                              void* d_out, int out_size, void* d_ws, size_t ws_size,
                              hipStream_t stream) {
  const float* X     = (const float*)d_in[0];
  const float* Winw  = (const float*)d_in[1];
  const float* Winb  = (const float*)d_in[2];
  const float* Wrw   = (const float*)d_in[3];
  const float* Wrb   = (const float*)d_in[4];
  const float* Woutw = (const float*)d_in[5];
  const float* Woutb = (const float*)d_in[6];
  float* out = (float*)d_out;

  char* ws = (char*)d_ws;
  u8*  W8     = (u8*)(ws);                     // 16 MB  i8 W_rec
  u8*  h0i    = (u8*)(ws + 16777216);          // 2 MB   i8 h
  u8*  h1i    = (u8*)(ws + 18874368);          // 2 MB   i8 h
  u16* h3bf   = (u16*)(ws + 20971520);         // 1 MB   bf16 h layer-3
  float* xin  = (float*)(ws + 22020096);       // 2 MB
  u16* Gp     = (u16*)(ws + 24117248);         // 8 MB   bf16 (2 ks x 4 l)
  float* Gp2  = (float*)(ws + 32505856);       // 12 MB  fp32 (2 ks x 3 terms)
  u16* Xhi    = (u16*)(ws + 45088768);         // 512 KB
  u16* Xlo    = (u16*)(ws + 45613056);         // 512 KB
  u16* Winh   = (u16*)(ws + 46137344);         // 4 MB
  u16* Winl   = (u16*)(ws + 50331648);         // 4 MB
  u16* Wouth  = (u16*)(ws + 54525952);         // 1 MB
  u16* Woutl  = (u16*)(ws + 55574528);         // 1 MB -> end 56623104

  // pack weights (every call; stateless)
  k_cvt_w8<<<16384, 256, 0, stream>>>(Wrw, (u32*)W8, 4194304);
  k_split2<<<256, 256, 0, stream>>>(X, Xhi, Xlo, 65536);
  k_split2<<<2048, 256, 0, stream>>>(Winw, Winh, Winl, 524288);
  k_split2<<<512, 256, 0, stream>>>(Woutw, Wouth, Woutl, 131072);
  hipMemsetAsync(h0i, 0, 2097152, stream);

  // x_in = X @ W_in^T (+bias), 3-term bf16 split, fp32 partials, split-K 2
  GemmArgs ax;
  ax.A[0] = Xhi; ax.A[1] = Xhi; ax.A[2] = Xlo; ax.A[3] = Xhi;
  ax.B[0] = Winh; ax.B[1] = Winl; ax.B[2] = Winh; ax.B[3] = Winh;
  ax.G = Gp2; ax.ldA = NIN; ax.ldB = NIN; ax.kiters = 8; ax.nl = 3;
  k_gemm<0, 2><<<192, 256, 0, stream>>>(ax);
  k_xin_fin<<<512, 256, 0, stream>>>(Gp2, Winb, xin);

  u8* hin = h0i;
  u8* hout = h1i;
  for (int t = 0; t < TSS; t++) {
    Rec8Args ar;
    ar.h = hin; ar.W8 = W8; ar.Gp = Gp;
    k_gemm8<<<256, 256, 0, stream>>>(ar);
    k_chain8<<<256, 256, 0, stream>>>(Gp, xin, Wrb, hout, h3bf);
    u8* tmp = hin; hin = hout; hout = tmp;
  }

  // h3bf holds the final layer-3 hidden state (written by last k_chain8)
  k_gemm_out<<<128, 64, 0, stream>>>(h3bf, Wouth, Woutl, Woutb, out);
}

// Round 15
// 591.568 us; speedup vs baseline: 12.7940x; 1.0076x over previous
//
#include <hip/hip_runtime.h>

typedef unsigned short u16;
typedef unsigned char u8;
typedef unsigned int u32;
typedef __bf16 bf16x8 __attribute__((ext_vector_type(8)));
typedef float f32x4 __attribute__((ext_vector_type(4)));
typedef u32 u32x4 __attribute__((ext_vector_type(4)));
typedef u32 u32x2 __attribute__((ext_vector_type(2)));
typedef u16 u16x4 __attribute__((ext_vector_type(4)));
typedef u16 u16x8 __attribute__((ext_vector_type(8)));
typedef int i32x4 __attribute__((ext_vector_type(4)));

#define NH 2048
#define BATCH 256
#define NIN 1024
#define NOUT 256
#define LAY 4
#define TSS 32
#define BK 64

#define SW_W 5747.0f  // 127 / (1/sqrt(2048)); |W|<0.0220971 -> |W*SW_W|<127.002
#define INV_DQ (1.0f / (127.0f * 5747.0f))

#define WAITVM(N) asm volatile("s_waitcnt vmcnt(" #N ")" ::: "memory")

__device__ __forceinline__ u16 f2bf(float f) {
  u32 u = __builtin_bit_cast(u32, f);
  u = (u + 0x7FFFu + ((u >> 16) & 1u)) >> 16;
  return (u16)u;
}
__device__ __forceinline__ float bf2f(u16 h) {
  u32 u = ((u32)h) << 16;
  return __builtin_bit_cast(float, u);
}

// sin for |x| <= ~6, abs err < ~4e-6 (degree-9 odd, pi range reduction)
__device__ __forceinline__ float fast_sin(float x) {
  float k = __builtin_rintf(x * 0.3183098861837907f);
  float r = __builtin_fmaf(k, -3.14159274101257324f, x);
  r = __builtin_fmaf(k, 8.742277657347586e-08f, r);
  float s = r * r;
  float p = __builtin_fmaf(s, 2.75573192e-06f, -1.98412698e-04f);
  p = __builtin_fmaf(s, p, 8.33333333e-03f);
  p = __builtin_fmaf(s, p, -1.66666667e-01f);
  p = r + r * s * p;
  int ki = (int)k;
  return (ki & 1) ? -p : p;
}

__device__ __forceinline__ bf16x8 ld_frag(const u16* p) {
  u32x4 r = *(const u32x4*)p;
  return __builtin_bit_cast(bf16x8, r);
}

__device__ __forceinline__ f32x4 mfma16(bf16x8 a, bf16x8 b, f32x4 c) {
  return __builtin_amdgcn_mfma_f32_16x16x32_bf16(a, b, c, 0, 0, 0);
}

// i8 MFMA via the documented gfx950 builtin (compiler handles all hazards)
__device__ __forceinline__ i32x4 mfma_i8(i32x4 a, i32x4 b, i32x4 c) {
  return __builtin_amdgcn_mfma_i32_16x16x64_i8(a, b, c, 0, 0, 0);
}

__device__ __forceinline__ void gload16(const void* g, void* lds) {
  __builtin_amdgcn_global_load_lds(
      (__attribute__((address_space(1))) u32*)g,
      (__attribute__((address_space(3))) u32*)lds, 16, 0, 0);
}

// ---------------- pack / convert kernels ----------------

// W fp32 -> i8 (scale SW_W), 4 elems/thread
__global__ __launch_bounds__(256) void k_cvt_w8(const float* __restrict__ in,
                                                u32* __restrict__ out, int n4) {
  int i = blockIdx.x * 256 + threadIdx.x;
  if (i >= n4) return;
  f32x4 v = ((const f32x4*)in)[i];
  u32 o = 0;
  #pragma unroll
  for (int j = 0; j < 4; j++) {
    int q = (int)__builtin_rintf(v[j] * SW_W);
    o |= ((u32)(q & 255)) << (8 * j);
  }
  out[i] = o;
}

__global__ __launch_bounds__(256) void k_split2(const float* __restrict__ in,
                                                u16* __restrict__ hi,
                                                u16* __restrict__ lo, int n4) {
  int i = blockIdx.x * 256 + threadIdx.x;
  if (i >= n4) return;
  f32x4 v = ((const f32x4*)in)[i];
  u16x4 hv, lv;
  #pragma unroll
  for (int j = 0; j < 4; j++) {
    u16 h = f2bf(v[j]);
    hv[j] = h;
    lv[j] = f2bf(v[j] - bf2f(h));
  }
  ((u16x4*)hi)[i] = hv;
  ((u16x4*)lo)[i] = lv;
}

// ---------------- bf16 GEMM (r5-proven 2-phase structure; x_in path) --------

struct GemmArgs {
  const u16* A[4];
  const u16* B[4];
  void* G;
  int ldA, ldB, kiters, nl;
};

template <int OBF, int NKS>
__global__ __launch_bounds__(256, 2) void k_gemm(GemmArgs args) {
  __shared__ alignas(16) u16 Ab[2][128 * BK];
  __shared__ alignas(16) u16 Bb[2][128 * BK];

  int bid = blockIdx.x;
  int nl = args.nl;
  int l = bid % nl;
  int t1 = bid / nl;
  int ks = t1 & (NKS - 1);
  int t2 = t1 / NKS;
  int nt = t2 & 15;
  int mt = t2 >> 4;

  int tid = threadIdx.x;
  int w = tid >> 6, lane = tid & 63;
  int l15 = lane & 15, l4 = lane >> 4;
  int ldA = args.ldA, ldB = args.ldB;
  int kiters = args.kiters;

  const u16* Ag = args.A[l] + (size_t)(mt * 128) * ldA + ks * (kiters * BK);
  const u16* Bg = args.B[l] + (size_t)(nt * 128) * ldB + ks * (kiters * BK);

  int srow = w * 32 + (lane >> 3);
  int csrc = ((lane & 7) ^ (lane >> 3)) * 8;
  int agoff[4], bgoff[4], lbase[4];
  #pragma unroll
  for (int j = 0; j < 4; j++) {
    agoff[j] = (srow + j * 8) * ldA + csrc;
    bgoff[j] = (srow + j * 8) * ldB + csrc;
    lbase[j] = w * 2048 + j * 512;
  }

  int wr = w >> 1, wc = w & 1;

  f32x4 zero = {0.f, 0.f, 0.f, 0.f};
  f32x4 acc[4][4];
  #pragma unroll
  for (int m = 0; m < 4; m++)
    #pragma unroll
    for (int n = 0; n < 4; n++) acc[m][n] = zero;

  auto stage = [&](int bufi, int kb) {
    int k0 = kb * BK;
    #pragma unroll
    for (int j = 0; j < 4; j++) {
      gload16(Ag + agoff[j] + k0, &Ab[bufi][lbase[j]]);
      gload16(Bg + bgoff[j] + k0, &Bb[bufi][lbase[j]]);
    }
  };
  auto compute = [&](int bufi) {
    #pragma unroll
    for (int kk = 0; kk < 2; kk++) {
      int swz = ((kk * 4 + l4) ^ (l15 & 7)) * 8;
      bf16x8 a[4], b[4];
      #pragma unroll
      for (int m = 0; m < 4; m++)
        a[m] = ld_frag(&Ab[bufi][(wr * 64 + m * 16 + l15) * BK + swz]);
      #pragma unroll
      for (int n = 0; n < 4; n++)
        b[n] = ld_frag(&Bb[bufi][(wc * 64 + n * 16 + l15) * BK + swz]);
      #pragma unroll
      for (int m = 0; m < 4; m++)
        #pragma unroll
        for (int n = 0; n < 4; n++)
          acc[m][n] = mfma16(a[m], b[n], acc[m][n]);
    }
  };

  stage(0, 0);
  stage(1, 1);

  int cur = 0;
  for (int kb = 0; kb < kiters - 2; kb++) {
    WAITVM(8);
    __builtin_amdgcn_s_barrier();
    compute(cur);
    __builtin_amdgcn_s_barrier();
    stage(cur, kb + 2);
    cur ^= 1;
  }
  WAITVM(8);
  __builtin_amdgcn_s_barrier();
  compute(cur);
  cur ^= 1;
  WAITVM(0);
  __builtin_amdgcn_s_barrier();
  compute(cur);

  size_t obase = ((size_t)(ks * nl + l) * BATCH + mt * 128) * NH + nt * 128;
  if (OBF) {
    u16* Go = (u16*)args.G + obase;
    #pragma unroll
    for (int m = 0; m < 4; m++) {
      int row = wr * 64 + m * 16 + l4 * 4;
      #pragma unroll
      for (int n = 0; n < 4; n++) {
        int col = wc * 64 + n * 16 + l15;
        #pragma unroll
        for (int r = 0; r < 4; r++)
          Go[(size_t)(row + r) * NH + col] = f2bf(acc[m][n][r]);
      }
    }
  } else {
    float* Go = (float*)args.G + obase;
    #pragma unroll
    for (int m = 0; m < 4; m++) {
      int row = wr * 64 + m * 16 + l4 * 4;
      #pragma unroll
      for (int n = 0; n < 4; n++) {
        int col = wc * 64 + n * 16 + l15;
        #pragma unroll
        for (int r = 0; r < 4; r++)
          Go[(size_t)(row + r) * NH + col] = acc[m][n][r];
      }
    }
  }
}

// ---------------- recurrent GEMM, int8: 64x128 tile, full K=2048, ks=1 ------
// r13/r14-proven addressing; ks=1 -> kiters=16 (tail fraction 12.5%), grid
// 256 = l(4) x mt(4, 64-row tiles) x nt(16). G is a single full-sum slab per
// layer (4 MB total) -> chain reads one slab; dequant rounds ONCE (better
// numerics than two bf16 partials). 6 gloads/buffer (A:2, B:4) -> WAITVM(6).
// Decode: l=bid&3, mt=(bid>>2)&3, nt=bid>>4; bid%8 pins (l, mt-parity) ->
// each XCD's L2 holds one layer's W (4 MB = its L2) + 128 A rows (256 KB).
// Wave tile 32x64: acc[2][4], 16 MFMA vs 6 ds_read_b128 per K-iter.

struct Rec8Args {
  const u8* h;    // [LAY][BATCH][NH] i8
  const u8* W8;   // [LAY][NH][NH] i8
  u16* Gp;        // 4 slabs [l][BATCH][NH] bf16
};

__global__ __launch_bounds__(256, 2) void k_gemm8(Rec8Args args) {
  __shared__ alignas(16) u8 Ab[2][64 * 128];   // 8 KB each
  __shared__ alignas(16) u8 Bb[2][128 * 128];  // 16 KB each

  int bid = blockIdx.x;
  int l = bid & 3;
  int mt = (bid >> 2) & 3;
  int nt = bid >> 4;

  int tid = threadIdx.x;
  int lane = tid & 63;
  int w = tid >> 6;
  int l15 = lane & 15, l4 = lane >> 4;
  int wr = w >> 1, wc = w & 1;  // wave tile 32x64

  const u8* Ag = args.h + (size_t)l * (BATCH * NH) + (size_t)(mt * 64) * NH;
  const u8* Bg = args.W8 + (size_t)l * (NH * NH) + (size_t)(nt * 128) * NH;

  // staging: LDS linear byte L = j*4096 + tid*16 -> row = j*32 + (tid>>3),
  // chunkpos = tid&7; inverse-swizzled source chunk = chunkpos ^ (row&7).
  int srow = tid >> 3;
  int csrc = ((tid & 7) ^ (srow & 7)) * 16;  // bytes
  int goffA[2], lbaseA[2], goffB[4], lbaseB[4];
  #pragma unroll
  for (int j = 0; j < 2; j++) {
    goffA[j] = (j * 32 + srow) * NH + csrc;
    lbaseA[j] = j * 4096 + tid * 16;
  }
  #pragma unroll
  for (int j = 0; j < 4; j++) {
    goffB[j] = (j * 32 + srow) * NH + csrc;
    lbaseB[j] = j * 4096 + tid * 16;
  }

  i32x4 zero = {0, 0, 0, 0};
  i32x4 acc[2][4];
  #pragma unroll
  for (int m = 0; m < 2; m++)
    #pragma unroll
    for (int n = 0; n < 4; n++) acc[m][n] = zero;

  auto stage = [&](int bufi, int kb) {
    int k0 = kb * 128;
    #pragma unroll
    for (int j = 0; j < 2; j++)
      gload16(Ag + goffA[j] + k0, &Ab[bufi][lbaseA[j]]);
    #pragma unroll
    for (int j = 0; j < 4; j++)
      gload16(Bg + goffB[j] + k0, &Bb[bufi][lbaseB[j]]);
  };
  auto compute = [&](int bufi) {
    #pragma unroll
    for (int kk = 0; kk < 2; kk++) {
      int swz = ((kk * 4 + l4) ^ (l15 & 7)) * 16;  // bytes
      i32x4 a[2], b[4];
      #pragma unroll
      for (int m = 0; m < 2; m++)
        a[m] = *(const i32x4*)&Ab[bufi][(wr * 32 + m * 16 + l15) * 128 + swz];
      #pragma unroll
      for (int n = 0; n < 4; n++)
        b[n] = *(const i32x4*)&Bb[bufi][(wc * 64 + n * 16 + l15) * 128 + swz];
      #pragma unroll
      for (int m = 0; m < 2; m++)
        #pragma unroll
        for (int n = 0; n < 4; n++)
          acc[m][n] = mfma_i8(a[m], b[n], acc[m][n]);
    }
  };

  stage(0, 0);
  stage(1, 1);

  int cur = 0;
  #pragma unroll 1
  for (int kb = 0; kb < 14; kb++) {  // kiters = 16
    WAITVM(6);
    __builtin_amdgcn_s_barrier();
    compute(cur);
    __builtin_amdgcn_s_barrier();
    stage(cur, kb + 2);
    cur ^= 1;
  }
  WAITVM(6);
  __builtin_amdgcn_s_barrier();
  compute(cur);
  cur ^= 1;
  WAITVM(0);
  __builtin_amdgcn_s_barrier();
  compute(cur);

  u16* Go = args.Gp + (size_t)l * (BATCH * NH) + (size_t)(mt * 64) * NH +
            nt * 128;
  #pragma unroll
  for (int m = 0; m < 2; m++) {
    int row = wr * 32 + m * 16 + l4 * 4;
    #pragma unroll
    for (int n = 0; n < 4; n++) {
      int col = wc * 64 + n * 16 + l15;
      #pragma unroll
      for (int r = 0; r < 4; r++)
        Go[(size_t)(row + r) * NH + col] = f2bf((float)acc[m][n][r] * INV_DQ);
    }
  }
}

// ---------------- sin chain: 1 bf16 G slab, 8 elems/thread, 16B loads -------
__global__ __launch_bounds__(256) void k_chain8(const u16* __restrict__ Gp,
                                                const float* __restrict__ x_in,
                                                const float* __restrict__ brec,
                                                u8* __restrict__ hq,
                                                u16* __restrict__ h3bf) {
  int i = blockIdx.x * 256 + threadIdx.x;  // 65536 threads, 8 elems each
  int e = i * 8;
  int col = e & (NH - 1);
  f32x4 p0 = *(const f32x4*)(x_in + e);
  f32x4 p1 = *(const f32x4*)(x_in + e + 4);
  #pragma unroll
  for (int l = 0; l < LAY; l++) {
    u16x8 g0 = *(const u16x8*)(Gp + (size_t)l * (BATCH * NH) + e);
    f32x4 b0 = *(const f32x4*)(brec + l * NH + col);
    f32x4 b1 = *(const f32x4*)(brec + l * NH + col + 4);
    u32x2 qw = {0u, 0u};
    u16x8 hv;
    #pragma unroll
    for (int j = 0; j < 4; j++) {
      float v = fast_sin(p0[j] + bf2f(g0[j]) + b0[j]);
      p0[j] = v;
      int q = (int)__builtin_rintf(v * 127.0f);
      qw[0] |= ((u32)(q & 255)) << (8 * j);
      hv[j] = f2bf(v);
    }
    #pragma unroll
    for (int j = 0; j < 4; j++) {
      float v = fast_sin(p1[j] + bf2f(g0[4 + j]) + b1[j]);
      p1[j] = v;
      int q = (int)__builtin_rintf(v * 127.0f);
      qw[1] |= ((u32)(q & 255)) << (8 * j);
      hv[4 + j] = f2bf(v);
    }
    *(u32x2*)(hq + (size_t)l * (BATCH * NH) + e) = qw;
    if (l == LAY - 1) *(u16x8*)(h3bf + e) = hv;
  }
}

// x_in = sum of 6 partial slices + bias (fp32 partials)
__global__ __launch_bounds__(256) void k_xin_fin(const float* __restrict__ Gp2,
                                                 const float* __restrict__ bin,
                                                 float* __restrict__ x_in) {
  int i = blockIdx.x * 256 + threadIdx.x;
  int e = i * 4;
  int col = e & (NH - 1);
  f32x4 s = *(const f32x4*)(bin + col);
  #pragma unroll
  for (int t = 0; t < 6; t++)
    s += *(const f32x4*)(Gp2 + (size_t)t * (BATCH * NH) + e);
  *(f32x4*)(x_in + e) = s;
}

// ---------------- output projection: out = h3 @ (Wh+Wl)^T + b ----------------
__global__ __launch_bounds__(64) void k_gemm_out(const u16* __restrict__ h3,
                                                 const u16* __restrict__ Wh,
                                                 const u16* __restrict__ Wl,
                                                 const float* __restrict__ bout,
                                                 float* __restrict__ out) {
  int bid = blockIdx.x;  // 128 = 8 mt x 16 nt
  int mt = bid & 7, nt = bid >> 3;
  int lane = threadIdx.x;
  int l15 = lane & 15, l4 = lane >> 4;
  f32x4 zero = {0.f, 0.f, 0.f, 0.f};
  f32x4 acc0 = zero, acc1 = zero;
  const u16* a0p = h3 + (size_t)(mt * 32 + l15) * NH + l4 * 8;
  const u16* a1p = a0p + 16 * NH;
  const u16* bhp = Wh + (size_t)(nt * 16 + l15) * NH + l4 * 8;
  const u16* blp = Wl + (size_t)(nt * 16 + l15) * NH + l4 * 8;
  for (int kb = 0; kb < 64; kb++) {
    bf16x8 a0 = ld_frag(a0p + kb * 32);
    bf16x8 a1 = ld_frag(a1p + kb * 32);
    bf16x8 bh = ld_frag(bhp + kb * 32);
    bf16x8 bl = ld_frag(blp + kb * 32);
    acc0 = mfma16(a0, bh, acc0);
    acc0 = mfma16(a0, bl, acc0);
    acc1 = mfma16(a1, bh, acc1);
    acc1 = mfma16(a1, bl, acc1);
  }
  float bo = bout[nt * 16 + l15];
  #pragma unroll
  for (int r = 0; r < 4; r++) {
    out[(size_t)(mt * 32 + l4 * 4 + r) * NOUT + nt * 16 + l15] = acc0[r] + bo;
    out[(size_t)(mt * 32 + 16 + l4 * 4 + r) * NOUT + nt * 16 + l15] = acc1[r] + bo;
  }
}

// ---------------- host ----------------

extern "C" void kernel_launch(void* const* d_in, const int* in_sizes, int n_in,
                              void* d_out, int out_size, void* d_ws, size_t ws_size,
                              hipStream_t stream) {
  const float* X     = (const float*)d_in[0];
  const float* Winw  = (const float*)d_in[1];
  const float* Winb  = (const float*)d_in[2];
  const float* Wrw   = (const float*)d_in[3];
  const float* Wrb   = (const float*)d_in[4];
  const float* Woutw = (const float*)d_in[5];
  const float* Woutb = (const float*)d_in[6];
  float* out = (float*)d_out;

  char* ws = (char*)d_ws;
  u8*  W8     = (u8*)(ws);                     // 16 MB  i8 W_rec
  u8*  h0i    = (u8*)(ws + 16777216);          // 2 MB   i8 h
  u8*  h1i    = (u8*)(ws + 18874368);          // 2 MB   i8 h
  u16* h3bf   = (u16*)(ws + 20971520);         // 1 MB   bf16 h layer-3
  float* xin  = (float*)(ws + 22020096);       // 2 MB
  u16* Gp     = (u16*)(ws + 24117248);         // 4 MB   bf16 (4 l)
  float* Gp2  = (float*)(ws + 28311552);       // 12 MB  fp32 (2 ks x 3 terms)
  u16* Xhi    = (u16*)(ws + 40894464);         // 512 KB
  u16* Xlo    = (u16*)(ws + 41418752);         // 512 KB
  u16* Winh   = (u16*)(ws + 41943040);         // 4 MB
  u16* Winl   = (u16*)(ws + 46137344);         // 4 MB
  u16* Wouth  = (u16*)(ws + 50331648);         // 1 MB
  u16* Woutl  = (u16*)(ws + 51380224);         // 1 MB -> end 52428800

  // pack weights (every call; stateless)
  k_cvt_w8<<<16384, 256, 0, stream>>>(Wrw, (u32*)W8, 4194304);
  k_split2<<<256, 256, 0, stream>>>(X, Xhi, Xlo, 65536);
  k_split2<<<2048, 256, 0, stream>>>(Winw, Winh, Winl, 524288);
  k_split2<<<512, 256, 0, stream>>>(Woutw, Wouth, Woutl, 131072);
  hipMemsetAsync(h0i, 0, 2097152, stream);

  // x_in = X @ W_in^T (+bias), 3-term bf16 split, fp32 partials, split-K 2
  GemmArgs ax;
  ax.A[0] = Xhi; ax.A[1] = Xhi; ax.A[2] = Xlo; ax.A[3] = Xhi;
  ax.B[0] = Winh; ax.B[1] = Winl; ax.B[2] = Winh; ax.B[3] = Winh;
  ax.G = Gp2; ax.ldA = NIN; ax.ldB = NIN; ax.kiters = 8; ax.nl = 3;
  k_gemm<0, 2><<<192, 256, 0, stream>>>(ax);
  k_xin_fin<<<512, 256, 0, stream>>>(Gp2, Winb, xin);

  u8* hin = h0i;
  u8* hout = h1i;
  for (int t = 0; t < TSS; t++) {
    Rec8Args ar;
    ar.h = hin; ar.W8 = W8; ar.Gp = Gp;
    k_gemm8<<<256, 256, 0, stream>>>(ar);
    k_chain8<<<256, 256, 0, stream>>>(Gp, xin, Wrb, hout, h3bf);
    u8* tmp = hin; hin = hout; hout = tmp;
  }

  // h3bf holds the final layer-3 hidden state (written by last k_chain8)
  k_gemm_out<<<128, 64, 0, stream>>>(h3bf, Wouth, Woutl, Woutb, out);
}